// Round 11
// baseline (336.266 us; speedup 1.0000x reference)
//
#include <hip/hip_runtime.h>

#define NN 100000
#define NE 600000
#define NP 100096   // 391*256, padded node count
#define NB 391
#define NBE 9375    // NE/64 edge blocks

typedef float v4    __attribute__((ext_vector_type(4)));
typedef float f32x4 __attribute__((ext_vector_type(4)));
typedef short s16x4 __attribute__((ext_vector_type(4)));
typedef short s16x8 __attribute__((ext_vector_type(8)));

__device__ __forceinline__ short f2bf(float f) {
    unsigned u = __float_as_uint(f);
    u = (u + 0x7fffu + ((u >> 16) & 1u)) >> 16;
    return (short)u;
}

// ---------------------------------------------------------------------------
// CSR construction: histogram -> scan -> fill (csr, cidx, rowp per slot)
// ---------------------------------------------------------------------------
__global__ __launch_bounds__(256) void hist_kernel(const int* __restrict__ ei,
                                                   int* __restrict__ deg) {
    int e = blockIdx.x * 256 + threadIdx.x;
    if (e < NE) atomicAdd(&deg[ei[e]], 1);
}

__global__ __launch_bounds__(256) void scan1_kernel(const int* __restrict__ deg,
                                                    int* __restrict__ partial,
                                                    int* __restrict__ bsum) {
    __shared__ int tmp[256];
    int t = threadIdx.x;
    int i = blockIdx.x * 256 + t;
    int v = deg[i];
    tmp[t] = v;
    __syncthreads();
    for (int off = 1; off < 256; off <<= 1) {
        int add = (t >= off) ? tmp[t - off] : 0;
        __syncthreads();
        tmp[t] += add;
        __syncthreads();
    }
    partial[i] = tmp[t] - v;
    if (t == 255) bsum[blockIdx.x] = tmp[255];
}

__global__ __launch_bounds__(512) void scan2_kernel(const int* __restrict__ bsum,
                                                    int* __restrict__ boff) {
    __shared__ int tmp[512];
    int t = threadIdx.x;
    int v = (t < NB) ? bsum[t] : 0;
    tmp[t] = v;
    __syncthreads();
    for (int off = 1; off < 512; off <<= 1) {
        int add = (t >= off) ? tmp[t - off] : 0;
        __syncthreads();
        tmp[t] += add;
        __syncthreads();
    }
    boff[t] = tmp[t] - v;
}

__global__ __launch_bounds__(256) void scan3_kernel(const int* __restrict__ partial,
                                                    const int* __restrict__ boff,
                                                    int* __restrict__ base,
                                                    int* __restrict__ cursor) {
    int i = blockIdx.x * 256 + threadIdx.x;
    int b = partial[i] + boff[blockIdx.x];
    base[i] = b;
    cursor[i] = b;
}

__global__ __launch_bounds__(256) void fill_kernel(const int* __restrict__ ei,
                                                   int* __restrict__ cursor,
                                                   int* __restrict__ csr,
                                                   int* __restrict__ cidx,
                                                   int* __restrict__ rowp) {
    int e = blockIdx.x * 256 + threadIdx.x;
    if (e < NE) {
        int r = ei[e];
        int p = atomicAdd(&cursor[r], 1);
        csr[p] = e;
        cidx[p] = ei[NE + e];
        rowp[p] = r;
    }
}

// ---------------------------------------------------------------------------
// zero agg rows of isolated (deg==0) nodes; everything else is overwritten.
// ---------------------------------------------------------------------------
__global__ __launch_bounds__(256) void zero_empty_kernel(const int* __restrict__ deg,
                                                         float* __restrict__ agg) {
    int n = blockIdx.x * 256 + threadIdx.x;
    if (n < NN && deg[n] == 0) {
        v4 z = {0.f, 0.f, 0.f, 0.f};
        float* dst = agg + (size_t)n * 128;
#pragma unroll
        for (int j = 0; j < 32; ++j) *(v4*)&dst[j * 4] = z;
    }
}

// ---------------------------------------------------------------------------
// Weight prep (bf16, B^T layouts, K contiguous)
// ---------------------------------------------------------------------------
__global__ __launch_bounds__(256) void prep_kernel(const float* __restrict__ W2a,
                                                   const float* __restrict__ W2b,
                                                   const float* __restrict__ W1a,
                                                   const float* __restrict__ W1b,
                                                   short* __restrict__ W2aT,
                                                   short* __restrict__ W2bT,
                                                   short* __restrict__ W1aT,
                                                   short* __restrict__ W1bT) {
    int idx = blockIdx.x * 256 + threadIdx.x;
    if (idx < 256 * 160) {
        int n = idx / 160, k = idx - n * 160;
        float v = 0.f;
        if (k < 128)       v = W2a[(2 + k) * 256 + n];
        else if (k == 128) v = W2a[0 * 256 + n];
        else if (k == 129) v = W2a[1 * 256 + n];
        else if (k == 130) v = W2a[130 * 256 + n];
        else if (k == 131) v = W2a[131 * 256 + n];
        W2aT[idx] = f2bf(v);
    }
    if (idx < 512 * 256) {
        int n = idx >> 8, k = idx & 255;
        W2bT[idx] = f2bf(W2b[k * 512 + n]);
    }
    if (idx < 64 * 32) {
        int n = idx >> 5, k = idx & 31;
        W1aT[idx] = (k < 4) ? f2bf(W1a[k * 64 + n]) : (short)0;
    }
    if (idx < 128 * 64) {
        int n = idx >> 6, k = idx & 63;
        W1bT[idx] = f2bf(W1b[k * 128 + n]);
    }
}

// ---------------------------------------------------------------------------
// Fused edge MFMA + segmented mean: 64 CSR slots/block (sorted by node).
// MFMA L1 (K=32) -> relu -> t1; L2 (K=64) -> +b1b -> hbf fp32 LDS.
// Then 128 threads (col each) walk the 64 slots, segmented by rowp:
//   complete node -> agg[n][c] = sum/d   (sole owner, no atomics)
//   first-partial -> pstart[blk][c]; last-partial -> pend[blk][c], eid[blk]=n
// Max degree << 64 so a node spans at most 2 blocks.
// ---------------------------------------------------------------------------
__global__ __launch_bounds__(256) void edge_fused_kernel(
    const float* __restrict__ x, const float* __restrict__ ea,
    const int* __restrict__ csr, const int* __restrict__ cidx,
    const int* __restrict__ rowp,
    const short* __restrict__ W1aT, const short* __restrict__ W1bT,
    const float* __restrict__ b1a, const float* __restrict__ b1b,
    const int* __restrict__ base, const int* __restrict__ deg,
    float* __restrict__ agg, float* __restrict__ pstart,
    float* __restrict__ pend, int* __restrict__ eid)
{
    __shared__ short in[64 * 40];
    __shared__ short t1[64 * 72];
    __shared__ float hbf[64 * 136];
    __shared__ int   rows[64];
    const int tid = threadIdx.x;
    const int p0 = blockIdx.x * 64;

    // ---- stage input tile + rows
    {
        int r = tid >> 2, q = tid & 3;
        s16x8 v = {0, 0, 0, 0, 0, 0, 0, 0};
        if (q == 0) {
            int p = p0 + r;
            int e = csr[p];
            int c = cidx[p];
            v[0] = f2bf(x[2 * c]);  v[1] = f2bf(x[2 * c + 1]);
            v[2] = f2bf(ea[2 * e]); v[3] = f2bf(ea[2 * e + 1]);
        }
        *(s16x8*)&in[r * 40 + q * 8] = v;
        if (tid < 64) rows[tid] = rowp[p0 + tid];
    }
    __syncthreads();

    const int lane = tid & 63, nw = tid >> 6;
    const int l15 = lane & 15, lk = lane >> 4;

    // ---- layer 1: K=32, wave nw covers cols nw*16..+16
    f32x4 acc1_0 = {0.f,0.f,0.f,0.f}, acc1_1 = {0.f,0.f,0.f,0.f};
    f32x4 acc1_2 = {0.f,0.f,0.f,0.f}, acc1_3 = {0.f,0.f,0.f,0.f};
    {
        int n = nw * 16 + l15;
        s16x8 b = *(const s16x8*)&W1aT[n * 32 + lk * 8];
        s16x8 a0 = *(const s16x8*)&in[(0 * 16 + l15) * 40 + lk * 8];
        s16x8 a1 = *(const s16x8*)&in[(1 * 16 + l15) * 40 + lk * 8];
        s16x8 a2 = *(const s16x8*)&in[(2 * 16 + l15) * 40 + lk * 8];
        s16x8 a3 = *(const s16x8*)&in[(3 * 16 + l15) * 40 + lk * 8];
        acc1_0 = __builtin_amdgcn_mfma_f32_16x16x32_bf16(a0, b, acc1_0, 0, 0, 0);
        acc1_1 = __builtin_amdgcn_mfma_f32_16x16x32_bf16(a1, b, acc1_1, 0, 0, 0);
        acc1_2 = __builtin_amdgcn_mfma_f32_16x16x32_bf16(a2, b, acc1_2, 0, 0, 0);
        acc1_3 = __builtin_amdgcn_mfma_f32_16x16x32_bf16(a3, b, acc1_3, 0, 0, 0);
    }
    {
        int n = nw * 16 + l15;
        float bias = b1a[n];
#pragma unroll
        for (int j = 0; j < 4; ++j) {
            t1[(0 * 16 + lk * 4 + j) * 72 + n] = f2bf(fmaxf(acc1_0[j] + bias, 0.f));
            t1[(1 * 16 + lk * 4 + j) * 72 + n] = f2bf(fmaxf(acc1_1[j] + bias, 0.f));
            t1[(2 * 16 + lk * 4 + j) * 72 + n] = f2bf(fmaxf(acc1_2[j] + bias, 0.f));
            t1[(3 * 16 + lk * 4 + j) * 72 + n] = f2bf(fmaxf(acc1_3[j] + bias, 0.f));
        }
    }
    __syncthreads();

    // ---- layer 2: K=64 (2 ksteps), wave nw covers cols nw*32..+32
    f32x4 acc2[4][2];
#pragma unroll
    for (int mf = 0; mf < 4; ++mf)
#pragma unroll
        for (int nf = 0; nf < 2; ++nf)
            acc2[mf][nf] = (f32x4){0.f, 0.f, 0.f, 0.f};

#pragma unroll
    for (int ks = 0; ks < 2; ++ks) {
        int cb = ks * 4 + lk;
        s16x8 a[4], b[2];
#pragma unroll
        for (int mf = 0; mf < 4; ++mf)
            a[mf] = *(const s16x8*)&t1[(mf * 16 + l15) * 72 + cb * 8];
#pragma unroll
        for (int nf = 0; nf < 2; ++nf) {
            int n = nw * 32 + nf * 16 + l15;
            b[nf] = *(const s16x8*)&W1bT[n * 64 + ks * 32 + lk * 8];
        }
#pragma unroll
        for (int mf = 0; mf < 4; ++mf)
#pragma unroll
            for (int nf = 0; nf < 2; ++nf)
                acc2[mf][nf] = __builtin_amdgcn_mfma_f32_16x16x32_bf16(
                    a[mf], b[nf], acc2[mf][nf], 0, 0, 0);
    }
    // ---- epilogue 2: + b1b -> hbf (fp32)
#pragma unroll
    for (int nf = 0; nf < 2; ++nf) {
        int n = nw * 32 + nf * 16 + l15;
        float bias = b1b[n];
#pragma unroll
        for (int mf = 0; mf < 4; ++mf)
#pragma unroll
            for (int j = 0; j < 4; ++j)
                hbf[(mf * 16 + lk * 4 + j) * 136 + n] = acc2[mf][nf][j] + bias;
    }
    __syncthreads();

    // ---- segmented reduction over 64 slots (threads 0..127, one col each)
    if (tid < 128) {
        const int c = tid;
        float sum = 0.f;
        int cur = rows[0];
        for (int i = 0; i < 64; ++i) {
            sum += hbf[i * 136 + c];
            bool segend = (i == 63) || (rows[i + 1] != cur);
            if (segend) {
                int bs = base[cur], d = deg[cur];
                bool startsHere = bs >= p0;
                bool endsHere   = bs + d <= p0 + 64;
                if (startsHere && endsHere) {
                    agg[(size_t)cur * 128 + c] = sum / (float)d;
                } else if (startsHere) {
                    pend[(size_t)blockIdx.x * 128 + c] = sum;       // continues next block
                } else if (endsHere) {
                    pstart[(size_t)blockIdx.x * 128 + c] = sum;     // started previous block
                }
                sum = 0.f;
                if (i < 63) cur = rows[i + 1];
            }
        }
        if (tid == 0) {
            int nlast = rows[63];
            bool lp = base[nlast] + deg[nlast] > p0 + 64;
            eid[blockIdx.x] = lp ? nlast : -1;
        }
    }
}

// ---------------------------------------------------------------------------
// Boundary fixup: node straddling blocks k/k+1 -> agg = (pend_k+pstart_k1)/d
// ---------------------------------------------------------------------------
__global__ __launch_bounds__(128) void fixup_kernel(
    const float* __restrict__ pend, const float* __restrict__ pstart,
    const int* __restrict__ eid, const int* __restrict__ deg,
    float* __restrict__ agg)
{
    int k = blockIdx.x;               // 0 .. NBE-2
    int n = eid[k];
    if (n < 0) return;
    int c = threadIdx.x;
    float s = pend[(size_t)k * 128 + c] + pstart[(size_t)(k + 1) * 128 + c];
    agg[(size_t)n * 128 + c] = s / (float)deg[n];
}

// ---------------------------------------------------------------------------
// Node MFMA kernel (unchanged, proven R9): 64 nodes/block, 8 waves.
// ---------------------------------------------------------------------------
__global__ __launch_bounds__(512, 2) void node_mfma_kernel(
    const float* __restrict__ x, const float* __restrict__ u,
    const int* __restrict__ batch,
    const float* __restrict__ agg,
    const short* __restrict__ W2aT, const short* __restrict__ W2bT,
    const float* __restrict__ b2a, const float* __restrict__ b2b,
    float* __restrict__ out)
{
    __shared__ short zb[64 * 192];
    __shared__ short tb[64 * 256];
    const int tid = threadIdx.x;
    const int node0 = blockIdx.x * 64;

#pragma unroll
    for (int it = 0; it < 4; ++it) {
        int idx = it * 512 + tid;
        int r = idx >> 5, c = idx & 31;
        int node = node0 + r;
        f32x4 v = {0.f, 0.f, 0.f, 0.f};
        if (node < NN) v = *(const f32x4*)&agg[(size_t)node * 128 + c * 4];
        s16x4 p;
        p[0] = f2bf(v[0]); p[1] = f2bf(v[1]); p[2] = f2bf(v[2]); p[3] = f2bf(v[3]);
        int ch = c >> 1;
        int sw = (ch & ~7) | ((ch ^ r) & 7);
        *(s16x4*)&zb[r * 192 + sw * 8 + (c & 1) * 4] = p;
    }
    if (tid < 64) {
        int r = tid, node = node0 + r;
        s16x8 p = {0, 0, 0, 0, 0, 0, 0, 0};
        if (node < NN) {
            p[0] = f2bf(x[node * 2]); p[1] = f2bf(x[node * 2 + 1]);
            int b = batch[node];
            p[2] = f2bf(u[b * 2]); p[3] = f2bf(u[b * 2 + 1]);
        }
        int sw = 16 | (r & 7);
        *(s16x8*)&zb[r * 192 + sw * 8] = p;
    } else if (tid < 256) {
        int t2 = tid - 64;
        int r = t2 & 63;
        int ch = 17 + (t2 >> 6);
        int sw = (ch & ~7) | ((ch ^ r) & 7);
        s16x8 zz = {0, 0, 0, 0, 0, 0, 0, 0};
        *(s16x8*)&zb[r * 192 + sw * 8] = zz;
    }
    __syncthreads();

    const int lane = tid & 63, wid = tid >> 6;
    const int l15 = lane & 15, lk = lane >> 4;
    const int nw = wid;

    f32x4 acc1[4][2];
#pragma unroll
    for (int mf = 0; mf < 4; ++mf)
#pragma unroll
        for (int nf = 0; nf < 2; ++nf)
            acc1[mf][nf] = (f32x4){0.f, 0.f, 0.f, 0.f};

#pragma unroll
    for (int ks = 0; ks < 5; ++ks) {
        s16x8 a[4], b[2];
        int cb = ks * 4 + lk;
#pragma unroll
        for (int mf = 0; mf < 4; ++mf) {
            int r = mf * 16 + l15;
            int sw = (cb & ~7) | ((cb ^ r) & 7);
            a[mf] = *(const s16x8*)&zb[r * 192 + sw * 8];
        }
#pragma unroll
        for (int nf = 0; nf < 2; ++nf) {
            int n = nw * 32 + nf * 16 + l15;
            b[nf] = *(const s16x8*)&W2aT[n * 160 + ks * 32 + lk * 8];
        }
#pragma unroll
        for (int mf = 0; mf < 4; ++mf)
#pragma unroll
            for (int nf = 0; nf < 2; ++nf)
                acc1[mf][nf] = __builtin_amdgcn_mfma_f32_16x16x32_bf16(
                    a[mf], b[nf], acc1[mf][nf], 0, 0, 0);
    }

#pragma unroll
    for (int nf = 0; nf < 2; ++nf) {
        int n = nw * 32 + nf * 16 + l15;
        float bias = b2a[n];
        int ch = n >> 3, off = n & 7;
#pragma unroll
        for (int mf = 0; mf < 4; ++mf) {
#pragma unroll
            for (int j = 0; j < 4; ++j) {
                int r = mf * 16 + lk * 4 + j;
                float vv = fmaxf(acc1[mf][nf][j] + bias, 0.f);
                int sw = (ch & ~7) | ((ch ^ r) & 7);
                tb[r * 256 + sw * 8 + off] = f2bf(vv);
            }
        }
    }
    __syncthreads();

    f32x4 acc2[4][4];
#pragma unroll
    for (int mf = 0; mf < 4; ++mf)
#pragma unroll
        for (int nf = 0; nf < 4; ++nf)
            acc2[mf][nf] = (f32x4){0.f, 0.f, 0.f, 0.f};

#pragma unroll
    for (int ks = 0; ks < 8; ++ks) {
        s16x8 a[4], b[4];
        int cb = ks * 4 + lk;
#pragma unroll
        for (int mf = 0; mf < 4; ++mf) {
            int r = mf * 16 + l15;
            int sw = (cb & ~7) | ((cb ^ r) & 7);
            a[mf] = *(const s16x8*)&tb[r * 256 + sw * 8];
        }
#pragma unroll
        for (int nf = 0; nf < 4; ++nf) {
            int n = nw * 64 + nf * 16 + l15;
            b[nf] = *(const s16x8*)&W2bT[n * 256 + ks * 32 + lk * 8];
        }
#pragma unroll
        for (int mf = 0; mf < 4; ++mf)
#pragma unroll
            for (int nf = 0; nf < 4; ++nf)
                acc2[mf][nf] = __builtin_amdgcn_mfma_f32_16x16x32_bf16(
                    a[mf], b[nf], acc2[mf][nf], 0, 0, 0);
    }

#pragma unroll
    for (int nf = 0; nf < 4; ++nf) {
        int n = nw * 64 + nf * 16 + l15;
        float bias = b2b[n];
#pragma unroll
        for (int mf = 0; mf < 4; ++mf) {
#pragma unroll
            for (int j = 0; j < 4; ++j) {
                int r = mf * 16 + lk * 4 + j;
                int node = node0 + r;
                if (node < NN)
                    out[(size_t)node * 512 + n] = acc2[mf][nf][j] + bias;
            }
        }
    }
}

extern "C" void kernel_launch(void* const* d_in, const int* in_sizes, int n_in,
                              void* d_out, int out_size, void* d_ws, size_t ws_size,
                              hipStream_t stream) {
    const float* x          = (const float*)d_in[0];
    const int*   edge_index = (const int*)d_in[1];
    const float* edge_attr  = (const float*)d_in[2];
    const float* u          = (const float*)d_in[3];
    const int*   batch      = (const int*)d_in[4];
    const float* W1a        = (const float*)d_in[5];
    const float* b1a        = (const float*)d_in[6];
    const float* W1b        = (const float*)d_in[7];
    const float* b1b        = (const float*)d_in[8];
    const float* W2a        = (const float*)d_in[9];
    const float* b2a        = (const float*)d_in[10];
    const float* W2b        = (const float*)d_in[11];
    const float* b2b        = (const float*)d_in[12];
    float* out = (float*)d_out;

    // workspace layout
    float* agg    = (float*)d_ws;                        // [NN,128] fp32
    short* W2aT   = (short*)(agg + (size_t)NN * 128);    // [256,160] bf16
    short* W2bT   = W2aT + 256 * 160;                    // [512,256] bf16
    short* W1aT   = W2bT + 512 * 256;                    // [64,32]   bf16
    short* W1bT   = W1aT + 64 * 32;                      // [128,64]  bf16
    int*   deg    = (int*)(W1bT + 128 * 64);             // [NP]
    int*   partial= deg + NP;                            // [NP]
    int*   bsum   = partial + NP;                        // [512]
    int*   boff   = bsum + 512;                          // [512]
    int*   base   = boff + 512;                          // [NP]
    int*   cursor = base + NP;                           // [NP]
    int*   csr    = cursor + NP;                         // [NE]
    int*   cidx   = csr + NE;                            // [NE]
    int*   rowp   = cidx + NE;                           // [NE]
    int*   eid    = rowp + NE;                           // [NBE]
    float* pstart = (float*)(eid + NBE);                 // [NBE,128]
    float* pend   = pstart + (size_t)NBE * 128;          // [NBE,128]

    hipMemsetAsync(deg, 0, NP * sizeof(int), stream);

    prep_kernel <<<512, 256, 0, stream>>>(W2a, W2b, W1a, W1b,
                                          W2aT, W2bT, W1aT, W1bT);
    hist_kernel <<<(NE + 255) / 256, 256, 0, stream>>>(edge_index, deg);
    scan1_kernel<<<NB, 256, 0, stream>>>(deg, partial, bsum);
    scan2_kernel<<<1, 512, 0, stream>>>(bsum, boff);
    scan3_kernel<<<NB, 256, 0, stream>>>(partial, boff, base, cursor);
    fill_kernel <<<(NE + 255) / 256, 256, 0, stream>>>(edge_index, cursor,
                                                       csr, cidx, rowp);
    zero_empty_kernel<<<NB, 256, 0, stream>>>(deg, agg);

    edge_fused_kernel<<<NBE, 256, 0, stream>>>(
        x, edge_attr, csr, cidx, rowp, W1aT, W1bT, b1a, b1b,
        base, deg, agg, pstart, pend, eid);

    fixup_kernel<<<NBE - 1, 128, 0, stream>>>(pend, pstart, eid, deg, agg);

    node_mfma_kernel<<<(NN + 63) / 64, 512, 0, stream>>>(
        x, u, batch, agg, W2aT, W2bT, b2a, b2b, out);
}

// Round 13
// 297.617 us; speedup vs baseline: 1.1299x; 1.1299x over previous
//
#include <hip/hip_runtime.h>

#define NN 100000
#define NE 600000
#define NP 100096   // 391*256, padded node count
#define NB 391
#define NBE 9375    // NE/64 edge blocks

typedef float v4    __attribute__((ext_vector_type(4)));
typedef float f32x4 __attribute__((ext_vector_type(4)));
typedef short s16x4 __attribute__((ext_vector_type(4)));
typedef short s16x8 __attribute__((ext_vector_type(8)));

__device__ __forceinline__ short f2bf(float f) {
    unsigned u = __float_as_uint(f);
    u = (u + 0x7fffu + ((u >> 16) & 1u)) >> 16;
    return (short)u;
}

// ---------------------------------------------------------------------------
// CSR construction: histogram -> scan -> fill (csr, cidx, rowp per slot)
// ---------------------------------------------------------------------------
__global__ __launch_bounds__(256) void hist_kernel(const int* __restrict__ ei,
                                                   int* __restrict__ deg) {
    int e = blockIdx.x * 256 + threadIdx.x;
    if (e < NE) atomicAdd(&deg[ei[e]], 1);
}

__global__ __launch_bounds__(256) void scan1_kernel(const int* __restrict__ deg,
                                                    int* __restrict__ partial,
                                                    int* __restrict__ bsum) {
    __shared__ int tmp[256];
    int t = threadIdx.x;
    int i = blockIdx.x * 256 + t;
    int v = deg[i];
    tmp[t] = v;
    __syncthreads();
    for (int off = 1; off < 256; off <<= 1) {
        int add = (t >= off) ? tmp[t - off] : 0;
        __syncthreads();
        tmp[t] += add;
        __syncthreads();
    }
    partial[i] = tmp[t] - v;
    if (t == 255) bsum[blockIdx.x] = tmp[255];
}

__global__ __launch_bounds__(512) void scan2_kernel(const int* __restrict__ bsum,
                                                    int* __restrict__ boff) {
    __shared__ int tmp[512];
    int t = threadIdx.x;
    int v = (t < NB) ? bsum[t] : 0;
    tmp[t] = v;
    __syncthreads();
    for (int off = 1; off < 512; off <<= 1) {
        int add = (t >= off) ? tmp[t - off] : 0;
        __syncthreads();
        tmp[t] += add;
        __syncthreads();
    }
    boff[t] = tmp[t] - v;
}

__global__ __launch_bounds__(256) void scan3_kernel(const int* __restrict__ partial,
                                                    const int* __restrict__ boff,
                                                    int* __restrict__ base,
                                                    int* __restrict__ cursor) {
    int i = blockIdx.x * 256 + threadIdx.x;
    int b = partial[i] + boff[blockIdx.x];
    base[i] = b;
    cursor[i] = b;
}

__global__ __launch_bounds__(256) void fill_kernel(const int* __restrict__ ei,
                                                   int* __restrict__ cursor,
                                                   int* __restrict__ csr,
                                                   int* __restrict__ cidx,
                                                   int* __restrict__ rowp) {
    int e = blockIdx.x * 256 + threadIdx.x;
    if (e < NE) {
        int r = ei[e];
        int p = atomicAdd(&cursor[r], 1);
        csr[p] = e;
        cidx[p] = ei[NE + e];
        rowp[p] = r;
    }
}

// ---------------------------------------------------------------------------
// zero agg rows of isolated (deg==0) nodes; everything else is overwritten.
// ---------------------------------------------------------------------------
__global__ __launch_bounds__(256) void zero_empty_kernel(const int* __restrict__ deg,
                                                         float* __restrict__ agg) {
    int n = blockIdx.x * 256 + threadIdx.x;
    if (n < NN && deg[n] == 0) {
        v4 z = {0.f, 0.f, 0.f, 0.f};
        float* dst = agg + (size_t)n * 128;
#pragma unroll
        for (int j = 0; j < 32; ++j) *(v4*)&dst[j * 4] = z;
    }
}

// ---------------------------------------------------------------------------
// Weight prep.
//  W2aF/W2bF: FRAG-MAJOR bf16 [nb][ks][lane][8] so a wave's fragment load is
//  one contiguous 1KB dwordx4 (old [n][k] layout was 512B lane-stride scatter).
//  element (nb,ks,lane,j) = W^T[n = nb*16+(lane&15)][k = ks*32+(lane>>4)*8+j]
//  W2a gets the z-reorder [agg(128), x(2), u(2), pad->160].
//  W1aT [64][32], W1bT [128][64] unchanged (edge kernel untouched).
// ---------------------------------------------------------------------------
__global__ __launch_bounds__(256) void prep_kernel(const float* __restrict__ W2a,
                                                   const float* __restrict__ W2b,
                                                   const float* __restrict__ W1a,
                                                   const float* __restrict__ W1b,
                                                   short* __restrict__ W2aF,
                                                   short* __restrict__ W2bF,
                                                   short* __restrict__ W1aT,
                                                   short* __restrict__ W1bT) {
    int idx = blockIdx.x * 256 + threadIdx.x;
    if (idx < 16 * 5 * 512) {                     // W2aF: 40960
        int j = idx & 7;
        int lane = (idx >> 3) & 63;
        int t2 = idx >> 9;
        int ks = t2 % 5, nb = t2 / 5;
        int n = nb * 16 + (lane & 15);
        int k = ks * 32 + (lane >> 4) * 8 + j;    // < 160
        float v = 0.f;
        if (k < 128)       v = W2a[(2 + k) * 256 + n];
        else if (k == 128) v = W2a[0 * 256 + n];
        else if (k == 129) v = W2a[1 * 256 + n];
        else if (k == 130) v = W2a[130 * 256 + n];
        else if (k == 131) v = W2a[131 * 256 + n];
        W2aF[idx] = f2bf(v);
    }
    if (idx < 32 * 8 * 512) {                     // W2bF: 131072
        int j = idx & 7;
        int lane = (idx >> 3) & 63;
        int t2 = idx >> 9;
        int ks = t2 & 7, nb = t2 >> 3;
        int n = nb * 16 + (lane & 15);
        int k = ks * 32 + (lane >> 4) * 8 + j;    // < 256
        W2bF[idx] = f2bf(W2b[k * 512 + n]);
    }
    if (idx < 64 * 32) {
        int n = idx >> 5, k = idx & 31;
        W1aT[idx] = (k < 4) ? f2bf(W1a[k * 64 + n]) : (short)0;
    }
    if (idx < 128 * 64) {
        int n = idx >> 6, k = idx & 63;
        W1bT[idx] = f2bf(W1b[k * 128 + n]);
    }
}

// ---------------------------------------------------------------------------
// Fused edge MFMA + segmented mean (unchanged from R11, proven correct).
// ---------------------------------------------------------------------------
__global__ __launch_bounds__(256) void edge_fused_kernel(
    const float* __restrict__ x, const float* __restrict__ ea,
    const int* __restrict__ csr, const int* __restrict__ cidx,
    const int* __restrict__ rowp,
    const short* __restrict__ W1aT, const short* __restrict__ W1bT,
    const float* __restrict__ b1a, const float* __restrict__ b1b,
    const int* __restrict__ base, const int* __restrict__ deg,
    float* __restrict__ agg, float* __restrict__ pstart,
    float* __restrict__ pend, int* __restrict__ eid)
{
    __shared__ short in[64 * 40];
    __shared__ short t1[64 * 72];
    __shared__ float hbf[64 * 136];
    __shared__ int   rows[64];
    const int tid = threadIdx.x;
    const int p0 = blockIdx.x * 64;

    {
        int r = tid >> 2, q = tid & 3;
        s16x8 v = {0, 0, 0, 0, 0, 0, 0, 0};
        if (q == 0) {
            int p = p0 + r;
            int e = csr[p];
            int c = cidx[p];
            v[0] = f2bf(x[2 * c]);  v[1] = f2bf(x[2 * c + 1]);
            v[2] = f2bf(ea[2 * e]); v[3] = f2bf(ea[2 * e + 1]);
        }
        *(s16x8*)&in[r * 40 + q * 8] = v;
        if (tid < 64) rows[tid] = rowp[p0 + tid];
    }
    __syncthreads();

    const int lane = tid & 63, nw = tid >> 6;
    const int l15 = lane & 15, lk = lane >> 4;

    f32x4 acc1_0 = {0.f,0.f,0.f,0.f}, acc1_1 = {0.f,0.f,0.f,0.f};
    f32x4 acc1_2 = {0.f,0.f,0.f,0.f}, acc1_3 = {0.f,0.f,0.f,0.f};
    {
        int n = nw * 16 + l15;
        s16x8 b = *(const s16x8*)&W1aT[n * 32 + lk * 8];
        s16x8 a0 = *(const s16x8*)&in[(0 * 16 + l15) * 40 + lk * 8];
        s16x8 a1 = *(const s16x8*)&in[(1 * 16 + l15) * 40 + lk * 8];
        s16x8 a2 = *(const s16x8*)&in[(2 * 16 + l15) * 40 + lk * 8];
        s16x8 a3 = *(const s16x8*)&in[(3 * 16 + l15) * 40 + lk * 8];
        acc1_0 = __builtin_amdgcn_mfma_f32_16x16x32_bf16(a0, b, acc1_0, 0, 0, 0);
        acc1_1 = __builtin_amdgcn_mfma_f32_16x16x32_bf16(a1, b, acc1_1, 0, 0, 0);
        acc1_2 = __builtin_amdgcn_mfma_f32_16x16x32_bf16(a2, b, acc1_2, 0, 0, 0);
        acc1_3 = __builtin_amdgcn_mfma_f32_16x16x32_bf16(a3, b, acc1_3, 0, 0, 0);
    }
    {
        int n = nw * 16 + l15;
        float bias = b1a[n];
#pragma unroll
        for (int j = 0; j < 4; ++j) {
            t1[(0 * 16 + lk * 4 + j) * 72 + n] = f2bf(fmaxf(acc1_0[j] + bias, 0.f));
            t1[(1 * 16 + lk * 4 + j) * 72 + n] = f2bf(fmaxf(acc1_1[j] + bias, 0.f));
            t1[(2 * 16 + lk * 4 + j) * 72 + n] = f2bf(fmaxf(acc1_2[j] + bias, 0.f));
            t1[(3 * 16 + lk * 4 + j) * 72 + n] = f2bf(fmaxf(acc1_3[j] + bias, 0.f));
        }
    }
    __syncthreads();

    f32x4 acc2[4][2];
#pragma unroll
    for (int mf = 0; mf < 4; ++mf)
#pragma unroll
        for (int nf = 0; nf < 2; ++nf)
            acc2[mf][nf] = (f32x4){0.f, 0.f, 0.f, 0.f};

#pragma unroll
    for (int ks = 0; ks < 2; ++ks) {
        int cb = ks * 4 + lk;
        s16x8 a[4], b[2];
#pragma unroll
        for (int mf = 0; mf < 4; ++mf)
            a[mf] = *(const s16x8*)&t1[(mf * 16 + l15) * 72 + cb * 8];
#pragma unroll
        for (int nf = 0; nf < 2; ++nf) {
            int n = nw * 32 + nf * 16 + l15;
            b[nf] = *(const s16x8*)&W1bT[n * 64 + ks * 32 + lk * 8];
        }
#pragma unroll
        for (int mf = 0; mf < 4; ++mf)
#pragma unroll
            for (int nf = 0; nf < 2; ++nf)
                acc2[mf][nf] = __builtin_amdgcn_mfma_f32_16x16x32_bf16(
                    a[mf], b[nf], acc2[mf][nf], 0, 0, 0);
    }
#pragma unroll
    for (int nf = 0; nf < 2; ++nf) {
        int n = nw * 32 + nf * 16 + l15;
        float bias = b1b[n];
#pragma unroll
        for (int mf = 0; mf < 4; ++mf)
#pragma unroll
            for (int j = 0; j < 4; ++j)
                hbf[(mf * 16 + lk * 4 + j) * 136 + n] = acc2[mf][nf][j] + bias;
    }
    __syncthreads();

    if (tid < 128) {
        const int c = tid;
        float sum = 0.f;
        int cur = rows[0];
        for (int i = 0; i < 64; ++i) {
            sum += hbf[i * 136 + c];
            bool segend = (i == 63) || (rows[i + 1] != cur);
            if (segend) {
                int bs = base[cur], d = deg[cur];
                bool startsHere = bs >= p0;
                bool endsHere   = bs + d <= p0 + 64;
                if (startsHere && endsHere) {
                    agg[(size_t)cur * 128 + c] = sum / (float)d;
                } else if (startsHere) {
                    pend[(size_t)blockIdx.x * 128 + c] = sum;
                } else if (endsHere) {
                    pstart[(size_t)blockIdx.x * 128 + c] = sum;
                }
                sum = 0.f;
                if (i < 63) cur = rows[i + 1];
            }
        }
        if (tid == 0) {
            int nlast = rows[63];
            bool lp = base[nlast] + deg[nlast] > p0 + 64;
            eid[blockIdx.x] = lp ? nlast : -1;
        }
    }
}

__global__ __launch_bounds__(128) void fixup_kernel(
    const float* __restrict__ pend, const float* __restrict__ pstart,
    const int* __restrict__ eid, const int* __restrict__ deg,
    float* __restrict__ agg)
{
    int k = blockIdx.x;
    int n = eid[k];
    if (n < 0) return;
    int c = threadIdx.x;
    float s = pend[(size_t)k * 128 + c] + pstart[(size_t)(k + 1) * 128 + c];
    agg[(size_t)n * 128 + c] = s / (float)deg[n];
}

// ---------------------------------------------------------------------------
// Node MFMA v2: swapped operand order mfma(W_frag, z_frag, acc) so D row = n,
// col = m  ->  each thread holds 4 CONSECUTIVE output columns:
//   epilogue1: 8x ds_write_b64 (was 32 scalar u16)
//   epilogue2: 16x global dwordx4 (was 64 scalar dword), f32x4 bias loads
// Frag-major weights: each fragment load = contiguous 1KB per wave.
// LDS union zb/tb = 32KB (extra barrier after L1; zb dead by then).
// ---------------------------------------------------------------------------
__global__ __launch_bounds__(512, 4) void node_mfma_kernel(
    const float* __restrict__ x, const float* __restrict__ u,
    const int* __restrict__ batch,
    const float* __restrict__ agg,
    const short* __restrict__ W2aF, const short* __restrict__ W2bF,
    const float* __restrict__ b2a, const float* __restrict__ b2b,
    float* __restrict__ out)
{
    __shared__ short lds[64 * 256];   // union: zb[64][192] then tb[64][256]
    const int tid = threadIdx.x;
    const int node0 = blockIdx.x * 64;

    // ---- stage agg -> zb (stride 192, chunk-XOR swizzle)
#pragma unroll
    for (int it = 0; it < 4; ++it) {
        int idx = it * 512 + tid;
        int r = idx >> 5, c = idx & 31;
        int node = node0 + r;
        f32x4 v = {0.f, 0.f, 0.f, 0.f};
        if (node < NN) v = *(const f32x4*)&agg[(size_t)node * 128 + c * 4];
        s16x4 p;
        p[0] = f2bf(v[0]); p[1] = f2bf(v[1]); p[2] = f2bf(v[2]); p[3] = f2bf(v[3]);
        int ch = c >> 1;
        int sw = (ch & ~7) | ((ch ^ r) & 7);
        *(s16x4*)&lds[r * 192 + sw * 8 + (c & 1) * 4] = p;
    }
    if (tid < 64) {
        int r = tid, node = node0 + r;
        s16x8 p = {0, 0, 0, 0, 0, 0, 0, 0};
        if (node < NN) {
            p[0] = f2bf(x[node * 2]); p[1] = f2bf(x[node * 2 + 1]);
            int b = batch[node];
            p[2] = f2bf(u[b * 2]); p[3] = f2bf(u[b * 2 + 1]);
        }
        int sw = 16 | (r & 7);
        *(s16x8*)&lds[r * 192 + sw * 8] = p;
    } else if (tid < 256) {
        int t2 = tid - 64;
        int r = t2 & 63;
        int ch = 17 + (t2 >> 6);
        int sw = (ch & ~7) | ((ch ^ r) & 7);
        s16x8 zz = {0, 0, 0, 0, 0, 0, 0, 0};
        *(s16x8*)&lds[r * 192 + sw * 8] = zz;
    }
    __syncthreads();

    const int lane = tid & 63, nw = tid >> 6;
    const int l15 = lane & 15, lk = lane >> 4;

    // ---- layer 1: K=160 (5 ksteps), wave covers cols nw*32..+32
    f32x4 acc1[4][2];
#pragma unroll
    for (int mf = 0; mf < 4; ++mf)
#pragma unroll
        for (int nf = 0; nf < 2; ++nf)
            acc1[mf][nf] = (f32x4){0.f, 0.f, 0.f, 0.f};

#pragma unroll
    for (int ks = 0; ks < 5; ++ks) {
        s16x8 a[4], w[2];
        int cb = ks * 4 + lk;
#pragma unroll
        for (int mf = 0; mf < 4; ++mf) {
            int r = mf * 16 + l15;
            int sw = (cb & ~7) | ((cb ^ r) & 7);
            a[mf] = *(const s16x8*)&lds[r * 192 + sw * 8];
        }
#pragma unroll
        for (int nf = 0; nf < 2; ++nf)
            w[nf] = *(const s16x8*)&W2aF[((((nw * 2 + nf) * 5) + ks) * 64 + lane) * 8];
#pragma unroll
        for (int mf = 0; mf < 4; ++mf)
#pragma unroll
            for (int nf = 0; nf < 2; ++nf)
                acc1[mf][nf] = __builtin_amdgcn_mfma_f32_16x16x32_bf16(
                    w[nf], a[mf], acc1[mf][nf], 0, 0, 0);   // swapped: D[n][m]
    }
    __syncthreads();   // zb dead; safe to overwrite union with tb

    // ---- epilogue 1: relu+bias -> tb[m][n] (stride 256), 4-consec n per write
#pragma unroll
    for (int nf = 0; nf < 2; ++nf) {
        int n0 = nw * 32 + nf * 16 + lk * 4;
        f32x4 bias = *(const f32x4*)&b2a[n0];
        int ch = n0 >> 3, off = n0 & 7;
#pragma unroll
        for (int mf = 0; mf < 4; ++mf) {
            int m = mf * 16 + l15;
            s16x4 pk;
#pragma unroll
            for (int j = 0; j < 4; ++j)
                pk[j] = f2bf(fmaxf(acc1[mf][nf][j] + bias[j], 0.f));
            int sw = (ch & ~7) | ((ch ^ m) & 7);
            *(s16x4*)&lds[m * 256 + sw * 8 + off] = pk;
        }
    }
    __syncthreads();

    // ---- layer 2: K=256 (8 ksteps), wave covers cols nw*64..+64
    f32x4 acc2[4][4];
#pragma unroll
    for (int mf = 0; mf < 4; ++mf)
#pragma unroll
        for (int nf = 0; nf < 4; ++nf)
            acc2[mf][nf] = (f32x4){0.f, 0.f, 0.f, 0.f};

#pragma unroll
    for (int ks = 0; ks < 8; ++ks) {
        s16x8 b[4], w[4];
        int cb = ks * 4 + lk;
#pragma unroll
        for (int mf = 0; mf < 4; ++mf) {
            int r = mf * 16 + l15;
            int sw = (cb & ~7) | ((cb ^ r) & 7);
            b[mf] = *(const s16x8*)&lds[r * 256 + sw * 8];
        }
#pragma unroll
        for (int nf = 0; nf < 4; ++nf)
            w[nf] = *(const s16x8*)&W2bF[((((nw * 4 + nf) * 8) + ks) * 64 + lane) * 8];
#pragma unroll
        for (int mf = 0; mf < 4; ++mf)
#pragma unroll
            for (int nf = 0; nf < 4; ++nf)
                acc2[mf][nf] = __builtin_amdgcn_mfma_f32_16x16x32_bf16(
                    w[nf], b[mf], acc2[mf][nf], 0, 0, 0);   // swapped: D[n][m]
    }

    // ---- epilogue 2: bias + f32x4 stores (4-consec n per thread)
#pragma unroll
    for (int nf = 0; nf < 4; ++nf) {
        int n0 = nw * 64 + nf * 16 + lk * 4;
        f32x4 bias = *(const f32x4*)&b2b[n0];
#pragma unroll
        for (int mf = 0; mf < 4; ++mf) {
            int node = node0 + mf * 16 + l15;
            if (node < NN) {
                f32x4 o = acc2[mf][nf] + bias;
                *(f32x4*)&out[(size_t)node * 512 + n0] = o;
            }
        }
    }
}

extern "C" void kernel_launch(void* const* d_in, const int* in_sizes, int n_in,
                              void* d_out, int out_size, void* d_ws, size_t ws_size,
                              hipStream_t stream) {
    const float* x          = (const float*)d_in[0];
    const int*   edge_index = (const int*)d_in[1];
    const float* edge_attr  = (const float*)d_in[2];
    const float* u          = (const float*)d_in[3];
    const int*   batch      = (const int*)d_in[4];
    const float* W1a        = (const float*)d_in[5];
    const float* b1a        = (const float*)d_in[6];
    const float* W1b        = (const float*)d_in[7];
    const float* b1b        = (const float*)d_in[8];
    const float* W2a        = (const float*)d_in[9];
    const float* b2a        = (const float*)d_in[10];
    const float* W2b        = (const float*)d_in[11];
    const float* b2b        = (const float*)d_in[12];
    float* out = (float*)d_out;

    // workspace layout
    float* agg    = (float*)d_ws;                        // [NN,128] fp32
    short* W2aF   = (short*)(agg + (size_t)NN * 128);    // [16*5*512] bf16
    short* W2bF   = W2aF + 16 * 5 * 512;                 // [32*8*512] bf16
    short* W1aT   = W2bF + 32 * 8 * 512;                 // [64,32]   bf16
    short* W1bT   = W1aT + 64 * 32;                      // [128,64]  bf16
    int*   deg    = (int*)(W1bT + 128 * 64);             // [NP]
    int*   partial= deg + NP;                            // [NP]
    int*   bsum   = partial + NP;                        // [512]
    int*   boff   = bsum + 512;                          // [512]
    int*   base   = boff + 512;                          // [NP]
    int*   cursor = base + NP;                           // [NP]
    int*   csr    = cursor + NP;                         // [NE]
    int*   cidx   = csr + NE;                            // [NE]
    int*   rowp   = cidx + NE;                           // [NE]
    int*   eid    = rowp + NE;                           // [NBE]
    float* pstart = (float*)(eid + NBE);                 // [NBE,128]
    float* pend   = pstart + (size_t)NBE * 128;          // [NBE,128]

    hipMemsetAsync(deg, 0, NP * sizeof(int), stream);

    prep_kernel <<<512, 256, 0, stream>>>(W2a, W2b, W1a, W1b,
                                          W2aF, W2bF, W1aT, W1bT);
    hist_kernel <<<(NE + 255) / 256, 256, 0, stream>>>(edge_index, deg);
    scan1_kernel<<<NB, 256, 0, stream>>>(deg, partial, bsum);
    scan2_kernel<<<1, 512, 0, stream>>>(bsum, boff);
    scan3_kernel<<<NB, 256, 0, stream>>>(partial, boff, base, cursor);
    fill_kernel <<<(NE + 255) / 256, 256, 0, stream>>>(edge_index, cursor,
                                                       csr, cidx, rowp);
    zero_empty_kernel<<<NB, 256, 0, stream>>>(deg, agg);

    edge_fused_kernel<<<NBE, 256, 0, stream>>>(
        x, edge_attr, csr, cidx, rowp, W1aT, W1bT, b1a, b1b,
        base, deg, agg, pstart, pend, eid);

    fixup_kernel<<<NBE - 1, 128, 0, stream>>>(pend, pstart, eid, deg, agg);

    node_mfma_kernel<<<(NN + 63) / 64, 512, 0, stream>>>(
        x, u, batch, agg, W2aF, W2bF, b2a, b2b, out);
}

// Round 14
// 263.737 us; speedup vs baseline: 1.2750x; 1.1285x over previous
//
#include <hip/hip_runtime.h>

#define NN 100000
#define NE 600000
#define NP 100096   // 391*256, padded node count
#define NB 391
#define NBE 9375    // NE/64 edge blocks

typedef float v4    __attribute__((ext_vector_type(4)));
typedef float f32x4 __attribute__((ext_vector_type(4)));
typedef short s16x4 __attribute__((ext_vector_type(4)));
typedef short s16x8 __attribute__((ext_vector_type(8)));

__device__ __forceinline__ short f2bf(float f) {
    unsigned u = __float_as_uint(f);
    u = (u + 0x7fffu + ((u >> 16) & 1u)) >> 16;
    return (short)u;
}
__device__ __forceinline__ float bf2f(unsigned short v) {
    return __uint_as_float(((unsigned)v) << 16);
}

// ---------------------------------------------------------------------------
// CSR construction: histogram -> scan -> fill.
// fill also pre-gathers the packed bf16 edge input [x[col],ea,0...] into
// in_csr[p][8] (random gather happens ONCE here, massively parallel).
// ---------------------------------------------------------------------------
__global__ __launch_bounds__(256) void hist_kernel(const int* __restrict__ ei,
                                                   int* __restrict__ deg) {
    int e = blockIdx.x * 256 + threadIdx.x;
    if (e < NE) atomicAdd(&deg[ei[e]], 1);
}

__global__ __launch_bounds__(256) void scan1_kernel(const int* __restrict__ deg,
                                                    int* __restrict__ partial,
                                                    int* __restrict__ bsum) {
    __shared__ int tmp[256];
    int t = threadIdx.x;
    int i = blockIdx.x * 256 + t;
    int v = deg[i];
    tmp[t] = v;
    __syncthreads();
    for (int off = 1; off < 256; off <<= 1) {
        int add = (t >= off) ? tmp[t - off] : 0;
        __syncthreads();
        tmp[t] += add;
        __syncthreads();
    }
    partial[i] = tmp[t] - v;
    if (t == 255) bsum[blockIdx.x] = tmp[255];
}

__global__ __launch_bounds__(512) void scan2_kernel(const int* __restrict__ bsum,
                                                    int* __restrict__ boff) {
    __shared__ int tmp[512];
    int t = threadIdx.x;
    int v = (t < NB) ? bsum[t] : 0;
    tmp[t] = v;
    __syncthreads();
    for (int off = 1; off < 512; off <<= 1) {
        int add = (t >= off) ? tmp[t - off] : 0;
        __syncthreads();
        tmp[t] += add;
        __syncthreads();
    }
    boff[t] = tmp[t] - v;
}

__global__ __launch_bounds__(256) void scan3_kernel(const int* __restrict__ partial,
                                                    const int* __restrict__ boff,
                                                    int* __restrict__ base,
                                                    int* __restrict__ cursor) {
    int i = blockIdx.x * 256 + threadIdx.x;
    int b = partial[i] + boff[blockIdx.x];
    base[i] = b;
    cursor[i] = b;
}

__global__ __launch_bounds__(256) void fill_kernel(const int* __restrict__ ei,
                                                   const float* __restrict__ x,
                                                   const float* __restrict__ ea,
                                                   int* __restrict__ cursor,
                                                   int* __restrict__ rowp,
                                                   short* __restrict__ in_csr) {
    int e = blockIdx.x * 256 + threadIdx.x;
    if (e < NE) {
        int r = ei[e];
        int c = ei[NE + e];
        int p = atomicAdd(&cursor[r], 1);
        rowp[p] = r;
        s16x8 v = {0, 0, 0, 0, 0, 0, 0, 0};
        v[0] = f2bf(x[2 * c]);  v[1] = f2bf(x[2 * c + 1]);
        v[2] = f2bf(ea[2 * e]); v[3] = f2bf(ea[2 * e + 1]);
        *(s16x8*)&in_csr[(size_t)p * 8] = v;
    }
}

// ---------------------------------------------------------------------------
// zero agg rows of isolated (deg==0) nodes; everything else is overwritten.
// ---------------------------------------------------------------------------
__global__ __launch_bounds__(256) void zero_empty_kernel(const int* __restrict__ deg,
                                                         float* __restrict__ agg) {
    int n = blockIdx.x * 256 + threadIdx.x;
    if (n < NN && deg[n] == 0) {
        v4 z = {0.f, 0.f, 0.f, 0.f};
        float* dst = agg + (size_t)n * 128;
#pragma unroll
        for (int j = 0; j < 32; ++j) *(v4*)&dst[j * 4] = z;
    }
}

// ---------------------------------------------------------------------------
// Weight prep (unchanged from R13): frag-major W2aF/W2bF, W1aT [64][32]
// (K=4 zero-padded), W1bT [128][64].
// ---------------------------------------------------------------------------
__global__ __launch_bounds__(256) void prep_kernel(const float* __restrict__ W2a,
                                                   const float* __restrict__ W2b,
                                                   const float* __restrict__ W1a,
                                                   const float* __restrict__ W1b,
                                                   short* __restrict__ W2aF,
                                                   short* __restrict__ W2bF,
                                                   short* __restrict__ W1aT,
                                                   short* __restrict__ W1bT) {
    int idx = blockIdx.x * 256 + threadIdx.x;
    if (idx < 16 * 5 * 512) {                     // W2aF: 40960
        int j = idx & 7;
        int lane = (idx >> 3) & 63;
        int t2 = idx >> 9;
        int ks = t2 % 5, nb = t2 / 5;
        int n = nb * 16 + (lane & 15);
        int k = ks * 32 + (lane >> 4) * 8 + j;    // < 160
        float v = 0.f;
        if (k < 128)       v = W2a[(2 + k) * 256 + n];
        else if (k == 128) v = W2a[0 * 256 + n];
        else if (k == 129) v = W2a[1 * 256 + n];
        else if (k == 130) v = W2a[130 * 256 + n];
        else if (k == 131) v = W2a[131 * 256 + n];
        W2aF[idx] = f2bf(v);
    }
    if (idx < 32 * 8 * 512) {                     // W2bF: 131072
        int j = idx & 7;
        int lane = (idx >> 3) & 63;
        int t2 = idx >> 9;
        int ks = t2 & 7, nb = t2 >> 3;
        int n = nb * 16 + (lane & 15);
        int k = ks * 32 + (lane >> 4) * 8 + j;    // < 256
        W2bF[idx] = f2bf(W2b[k * 512 + n]);
    }
    if (idx < 64 * 32) {
        int n = idx >> 5, k = idx & 31;
        W1aT[idx] = (k < 4) ? f2bf(W1a[k * 64 + n]) : (short)0;
    }
    if (idx < 128 * 64) {
        int n = idx >> 6, k = idx & 63;
        W1bT[idx] = f2bf(W1b[k * 128 + n]);
    }
}

// ---------------------------------------------------------------------------
// Edge fused v2: 64 CSR slots/block, 4 waves.
//  - staging: one coalesced b128 load/row from pre-gathered in_csr
//  - swapped-operand MFMA (D[n][m]) -> b64 vector epilogue writes
//  - hbf stored bf16 (halves LDS: ~34KB -> 4 blocks/CU)
//  - segmented reduce split into two 32-slot halves (all 256 threads)
//    with LDS mid-merge; block-boundary partials to pstart/pend as before.
// ---------------------------------------------------------------------------
__global__ __launch_bounds__(256) void edge_fused_kernel(
    const short* __restrict__ in_csr, const int* __restrict__ rowp,
    const short* __restrict__ W1aT, const short* __restrict__ W1bT,
    const float* __restrict__ b1a, const float* __restrict__ b1b,
    const int* __restrict__ base, const int* __restrict__ deg,
    float* __restrict__ agg, float* __restrict__ pstart,
    float* __restrict__ pend, int* __restrict__ eid)
{
    __shared__ short in[64 * 48];     // [edge][k] K=32 (cols 4..31 zero)
    __shared__ short t1[64 * 72];     // [edge][64]
    __shared__ short hbf[64 * 136];   // [edge][128] bf16
    __shared__ int   rows[64];
    __shared__ float midlo[128], midhi[128];
    const int tid = threadIdx.x;
    const int p0 = blockIdx.x * 64;

    // ---- stage
    if (tid < 64) {
        *(s16x8*)&in[tid * 48] = *(const s16x8*)&in_csr[(size_t)(p0 + tid) * 8];
        rows[tid] = rowp[p0 + tid];
    } else {
        int t2 = tid - 64;            // 0..191: zero cols 8..31 of all rows
        int r = t2 / 3, ch = t2 % 3;
        s16x8 z = {0, 0, 0, 0, 0, 0, 0, 0};
        *(s16x8*)&in[r * 48 + 8 + ch * 8] = z;
    }
    __syncthreads();

    const int lane = tid & 63, nw = tid >> 6;
    const int l15 = lane & 15, lk = lane >> 4;

    // ---- L1 swapped: A=W1a(t1col,k) B=in(edge,k); wave nw -> t1cols nw*16..+16
    f32x4 a1[4];
#pragma unroll
    for (int bf = 0; bf < 4; ++bf) a1[bf] = (f32x4){0.f, 0.f, 0.f, 0.f};
    {
        s16x8 wA = *(const s16x8*)&W1aT[(nw * 16 + l15) * 32 + lk * 8];
#pragma unroll
        for (int bf = 0; bf < 4; ++bf) {
            s16x8 bI = *(const s16x8*)&in[(bf * 16 + l15) * 48 + lk * 8];
            a1[bf] = __builtin_amdgcn_mfma_f32_16x16x32_bf16(wA, bI, a1[bf], 0, 0, 0);
        }
    }
    // ---- epilogue1: thread owns t1[edge=bf*16+l15][t1col0..+3], t1col0=nw*16+lk*4
    {
        f32x4 bias = *(const f32x4*)&b1a[nw * 16 + lk * 4];
#pragma unroll
        for (int bf = 0; bf < 4; ++bf) {
            s16x4 pk;
#pragma unroll
            for (int j = 0; j < 4; ++j)
                pk[j] = f2bf(fmaxf(a1[bf][j] + bias[j], 0.f));
            *(s16x4*)&t1[(bf * 16 + l15) * 72 + nw * 16 + lk * 4] = pk;
        }
    }
    __syncthreads();

    // ---- L2 swapped: A=W1b(outcol,k=64) B=t1(edge,k); wave nw -> outcols nw*32..+32
    f32x4 a2[2][4];
#pragma unroll
    for (int af = 0; af < 2; ++af)
#pragma unroll
        for (int bf = 0; bf < 4; ++bf) a2[af][bf] = (f32x4){0.f, 0.f, 0.f, 0.f};

#pragma unroll
    for (int ks = 0; ks < 2; ++ks) {
        s16x8 w[2], b[4];
#pragma unroll
        for (int af = 0; af < 2; ++af)
            w[af] = *(const s16x8*)&W1bT[((nw * 2 + af) * 16 + l15) * 64 + ks * 32 + lk * 8];
#pragma unroll
        for (int bf = 0; bf < 4; ++bf)
            b[bf] = *(const s16x8*)&t1[(bf * 16 + l15) * 72 + ks * 32 + lk * 8];
#pragma unroll
        for (int af = 0; af < 2; ++af)
#pragma unroll
            for (int bf = 0; bf < 4; ++bf)
                a2[af][bf] = __builtin_amdgcn_mfma_f32_16x16x32_bf16(
                    w[af], b[bf], a2[af][bf], 0, 0, 0);
    }
    // ---- epilogue2: thread owns hbf[edge=bf*16+l15][outcol0..+3]
#pragma unroll
    for (int af = 0; af < 2; ++af) {
        int oc0 = (nw * 2 + af) * 16 + lk * 4;
        f32x4 bias = *(const f32x4*)&b1b[oc0];
#pragma unroll
        for (int bf = 0; bf < 4; ++bf) {
            s16x4 pk;
#pragma unroll
            for (int j = 0; j < 4; ++j)
                pk[j] = f2bf(a2[af][bf][j] + bias[j]);
            *(s16x4*)&hbf[(bf * 16 + l15) * 136 + oc0] = pk;
        }
    }
    __syncthreads();

    // ---- segmented reduce: two 32-slot halves, all 256 threads
    {
        const int half = tid >> 7;
        const int c = tid & 127;
        const int slo = half * 32, shi = slo + 32;
        float sum = 0.f;
        int cur = rows[slo];
        bool first = true;
        for (int i = slo; i < shi; ++i) {
            sum += bf2f((unsigned short)hbf[i * 136 + c]);
            bool segend = (i == shi - 1) || (rows[i + 1] != cur);
            if (segend) {
                bool crossMid  = (half == 0) && (i == 31) && (rows[32] == cur);
                bool fromLower = (half == 1) && first && (rows[31] == cur);
                if (crossMid) {
                    midlo[c] = sum;
                } else if (fromLower) {
                    midhi[c] = sum;
                } else {
                    int bs = base[cur], d = deg[cur];
                    bool sh = bs >= p0, eh = bs + d <= p0 + 64;
                    if (sh && eh)      agg[(size_t)cur * 128 + c] = sum / (float)d;
                    else if (sh)       pend[(size_t)blockIdx.x * 128 + c] = sum;
                    else if (eh)       pstart[(size_t)blockIdx.x * 128 + c] = sum;
                }
                sum = 0.f;
                first = false;
                if (i < shi - 1) cur = rows[i + 1];
            }
        }
    }
    __syncthreads();
    // ---- mid-merge: the (single) node crossing slot 31/32
    if (tid < 128 && rows[31] == rows[32]) {
        int c = tid, cur = rows[32];
        float s = midlo[c] + midhi[c];
        int bs = base[cur], d = deg[cur];
        bool sh = bs >= p0, eh = bs + d <= p0 + 64;
        if (sh && eh)      agg[(size_t)cur * 128 + c] = s / (float)d;
        else if (sh)       pend[(size_t)blockIdx.x * 128 + c] = s;
        else if (eh)       pstart[(size_t)blockIdx.x * 128 + c] = s;
    }
    if (tid == 0) {
        int nlast = rows[63];
        eid[blockIdx.x] = (base[nlast] + deg[nlast] > p0 + 64) ? nlast : -1;
    }
}

// ---------------------------------------------------------------------------
// Boundary fixup: node straddling blocks k/k+1 -> agg = (pend_k+pstart_k1)/d
// ---------------------------------------------------------------------------
__global__ __launch_bounds__(128) void fixup_kernel(
    const float* __restrict__ pend, const float* __restrict__ pstart,
    const int* __restrict__ eid, const int* __restrict__ deg,
    float* __restrict__ agg)
{
    int k = blockIdx.x;
    int n = eid[k];
    if (n < 0) return;
    int c = threadIdx.x;
    float s = pend[(size_t)k * 128 + c] + pstart[(size_t)(k + 1) * 128 + c];
    agg[(size_t)n * 128 + c] = s / (float)deg[n];
}

// ---------------------------------------------------------------------------
// Node MFMA v2 (unchanged from R13 — proven): swapped operands, frag-major
// weights, LDS union, vectorized epilogues.
// ---------------------------------------------------------------------------
__global__ __launch_bounds__(512, 4) void node_mfma_kernel(
    const float* __restrict__ x, const float* __restrict__ u,
    const int* __restrict__ batch,
    const float* __restrict__ agg,
    const short* __restrict__ W2aF, const short* __restrict__ W2bF,
    const float* __restrict__ b2a, const float* __restrict__ b2b,
    float* __restrict__ out)
{
    __shared__ short lds[64 * 256];   // union: zb[64][192] then tb[64][256]
    const int tid = threadIdx.x;
    const int node0 = blockIdx.x * 64;

#pragma unroll
    for (int it = 0; it < 4; ++it) {
        int idx = it * 512 + tid;
        int r = idx >> 5, c = idx & 31;
        int node = node0 + r;
        f32x4 v = {0.f, 0.f, 0.f, 0.f};
        if (node < NN) v = *(const f32x4*)&agg[(size_t)node * 128 + c * 4];
        s16x4 p;
        p[0] = f2bf(v[0]); p[1] = f2bf(v[1]); p[2] = f2bf(v[2]); p[3] = f2bf(v[3]);
        int ch = c >> 1;
        int sw = (ch & ~7) | ((ch ^ r) & 7);
        *(s16x4*)&lds[r * 192 + sw * 8 + (c & 1) * 4] = p;
    }
    if (tid < 64) {
        int r = tid, node = node0 + r;
        s16x8 p = {0, 0, 0, 0, 0, 0, 0, 0};
        if (node < NN) {
            p[0] = f2bf(x[node * 2]); p[1] = f2bf(x[node * 2 + 1]);
            int b = batch[node];
            p[2] = f2bf(u[b * 2]); p[3] = f2bf(u[b * 2 + 1]);
        }
        int sw = 16 | (r & 7);
        *(s16x8*)&lds[r * 192 + sw * 8] = p;
    } else if (tid < 256) {
        int t2 = tid - 64;
        int r = t2 & 63;
        int ch = 17 + (t2 >> 6);
        int sw = (ch & ~7) | ((ch ^ r) & 7);
        s16x8 zz = {0, 0, 0, 0, 0, 0, 0, 0};
        *(s16x8*)&lds[r * 192 + sw * 8] = zz;
    }
    __syncthreads();

    const int lane = tid & 63, nw = tid >> 6;
    const int l15 = lane & 15, lk = lane >> 4;

    f32x4 acc1[4][2];
#pragma unroll
    for (int mf = 0; mf < 4; ++mf)
#pragma unroll
        for (int nf = 0; nf < 2; ++nf)
            acc1[mf][nf] = (f32x4){0.f, 0.f, 0.f, 0.f};

#pragma unroll
    for (int ks = 0; ks < 5; ++ks) {
        s16x8 a[4], w[2];
        int cb = ks * 4 + lk;
#pragma unroll
        for (int mf = 0; mf < 4; ++mf) {
            int r = mf * 16 + l15;
            int sw = (cb & ~7) | ((cb ^ r) & 7);
            a[mf] = *(const s16x8*)&lds[r * 192 + sw * 8];
        }
#pragma unroll
        for (int nf = 0; nf < 2; ++nf)
            w[nf] = *(const s16x8*)&W2aF[((((nw * 2 + nf) * 5) + ks) * 64 + lane) * 8];
#pragma unroll
        for (int mf = 0; mf < 4; ++mf)
#pragma unroll
            for (int nf = 0; nf < 2; ++nf)
                acc1[mf][nf] = __builtin_amdgcn_mfma_f32_16x16x32_bf16(
                    w[nf], a[mf], acc1[mf][nf], 0, 0, 0);
    }
    __syncthreads();

#pragma unroll
    for (int nf = 0; nf < 2; ++nf) {
        int n0 = nw * 32 + nf * 16 + lk * 4;
        f32x4 bias = *(const f32x4*)&b2a[n0];
        int ch = n0 >> 3, off = n0 & 7;
#pragma unroll
        for (int mf = 0; mf < 4; ++mf) {
            int m = mf * 16 + l15;
            s16x4 pk;
#pragma unroll
            for (int j = 0; j < 4; ++j)
                pk[j] = f2bf(fmaxf(acc1[mf][nf][j] + bias[j], 0.f));
            int sw = (ch & ~7) | ((ch ^ m) & 7);
            *(s16x4*)&lds[m * 256 + sw * 8 + off] = pk;
        }
    }
    __syncthreads();

    f32x4 acc2[4][4];
#pragma unroll
    for (int mf = 0; mf < 4; ++mf)
#pragma unroll
        for (int nf = 0; nf < 4; ++nf)
            acc2[mf][nf] = (f32x4){0.f, 0.f, 0.f, 0.f};

#pragma unroll
    for (int ks = 0; ks < 8; ++ks) {
        s16x8 b[4], w[4];
        int cb = ks * 4 + lk;
#pragma unroll
        for (int mf = 0; mf < 4; ++mf) {
            int r = mf * 16 + l15;
            int sw = (cb & ~7) | ((cb ^ r) & 7);
            b[mf] = *(const s16x8*)&lds[r * 256 + sw * 8];
        }
#pragma unroll
        for (int nf = 0; nf < 4; ++nf)
            w[nf] = *(const s16x8*)&W2bF[((((nw * 4 + nf) * 8) + ks) * 64 + lane) * 8];
#pragma unroll
        for (int mf = 0; mf < 4; ++mf)
#pragma unroll
            for (int nf = 0; nf < 4; ++nf)
                acc2[mf][nf] = __builtin_amdgcn_mfma_f32_16x16x32_bf16(
                    w[nf], b[mf], acc2[mf][nf], 0, 0, 0);
    }

#pragma unroll
    for (int nf = 0; nf < 4; ++nf) {
        int n0 = nw * 64 + nf * 16 + lk * 4;
        f32x4 bias = *(const f32x4*)&b2b[n0];
#pragma unroll
        for (int mf = 0; mf < 4; ++mf) {
            int node = node0 + mf * 16 + l15;
            if (node < NN) {
                f32x4 o = acc2[mf][nf] + bias;
                *(f32x4*)&out[(size_t)node * 512 + n0] = o;
            }
        }
    }
}

extern "C" void kernel_launch(void* const* d_in, const int* in_sizes, int n_in,
                              void* d_out, int out_size, void* d_ws, size_t ws_size,
                              hipStream_t stream) {
    const float* x          = (const float*)d_in[0];
    const int*   edge_index = (const int*)d_in[1];
    const float* edge_attr  = (const float*)d_in[2];
    const float* u          = (const float*)d_in[3];
    const int*   batch      = (const int*)d_in[4];
    const float* W1a        = (const float*)d_in[5];
    const float* b1a        = (const float*)d_in[6];
    const float* W1b        = (const float*)d_in[7];
    const float* b1b        = (const float*)d_in[8];
    const float* W2a        = (const float*)d_in[9];
    const float* b2a        = (const float*)d_in[10];
    const float* W2b        = (const float*)d_in[11];
    const float* b2b        = (const float*)d_in[12];
    float* out = (float*)d_out;

    // workspace layout
    float* agg    = (float*)d_ws;                        // [NN,128] fp32
    short* W2aF   = (short*)(agg + (size_t)NN * 128);    // [16*5*512] bf16
    short* W2bF   = W2aF + 16 * 5 * 512;                 // [32*8*512] bf16
    short* W1aT   = W2bF + 32 * 8 * 512;                 // [64,32]   bf16
    short* W1bT   = W1aT + 64 * 32;                      // [128,64]  bf16
    int*   deg    = (int*)(W1bT + 128 * 64);             // [NP]
    int*   partial= deg + NP;                            // [NP]
    int*   bsum   = partial + NP;                        // [512]
    int*   boff   = bsum + 512;                          // [512]
    int*   base   = boff + 512;                          // [NP]
    int*   cursor = base + NP;                           // [NP]
    int*   rowp   = cursor + NP;                         // [NE]
    int*   eid    = rowp + NE;                           // [NBE]
    float* pstart = (float*)(eid + NBE);                 // [NBE,128]
    float* pend   = pstart + (size_t)NBE * 128;          // [NBE,128]
    short* in_csr = (short*)(pend + (size_t)NBE * 128);  // [NE,8] bf16

    hipMemsetAsync(deg, 0, NP * sizeof(int), stream);

    prep_kernel <<<512, 256, 0, stream>>>(W2a, W2b, W1a, W1b,
                                          W2aF, W2bF, W1aT, W1bT);
    hist_kernel <<<(NE + 255) / 256, 256, 0, stream>>>(edge_index, deg);
    scan1_kernel<<<NB, 256, 0, stream>>>(deg, partial, bsum);
    scan2_kernel<<<1, 512, 0, stream>>>(bsum, boff);
    scan3_kernel<<<NB, 256, 0, stream>>>(partial, boff, base, cursor);
    fill_kernel <<<(NE + 255) / 256, 256, 0, stream>>>(edge_index, x, edge_attr,
                                                       cursor, rowp, in_csr);
    zero_empty_kernel<<<NB, 256, 0, stream>>>(deg, agg);

    edge_fused_kernel<<<NBE, 256, 0, stream>>>(
        in_csr, rowp, W1aT, W1bT, b1a, b1b,
        base, deg, agg, pstart, pend, eid);

    fixup_kernel<<<NBE - 1, 128, 0, stream>>>(pend, pstart, eid, deg, agg);

    node_mfma_kernel<<<(NN + 63) / 64, 512, 0, stream>>>(
        x, u, batch, agg, W2aF, W2bF, b2a, b2b, out);
}

// Round 15
// 244.334 us; speedup vs baseline: 1.3763x; 1.0794x over previous
//
#include <hip/hip_runtime.h>

#define NN 100000
#define NE 600000
#define NP 100096   // 391*256, padded node count
#define NB 391
#define NBE 9375    // NE/64 edge blocks

typedef float v4    __attribute__((ext_vector_type(4)));
typedef float f32x4 __attribute__((ext_vector_type(4)));
typedef short s16x4 __attribute__((ext_vector_type(4)));
typedef short s16x8 __attribute__((ext_vector_type(8)));

__device__ __forceinline__ short f2bf(float f) {
    unsigned u = __float_as_uint(f);
    u = (u + 0x7fffu + ((u >> 16) & 1u)) >> 16;
    return (short)u;
}
__device__ __forceinline__ float bf2f(unsigned short v) {
    return __uint_as_float(((unsigned)v) << 16);
}

// ---------------------------------------------------------------------------
// CSR construction: histogram -> scan (2 levels) -> fill.
// fill computes each slot inline (partial + boff + per-row atomic counter),
// eliminating the old scan3/cursor pass, and pre-gathers the packed bf16
// edge input [x[col],ea,0...] into in_csr[p][8].
// ---------------------------------------------------------------------------
__global__ __launch_bounds__(256) void hist_kernel(const int* __restrict__ ei,
                                                   int* __restrict__ deg) {
    int e = blockIdx.x * 256 + threadIdx.x;
    if (e < NE) atomicAdd(&deg[ei[e]], 1);
}

__global__ __launch_bounds__(256) void scan1_kernel(const int* __restrict__ deg,
                                                    int* __restrict__ partial,
                                                    int* __restrict__ bsum) {
    __shared__ int tmp[256];
    int t = threadIdx.x;
    int i = blockIdx.x * 256 + t;
    int v = deg[i];
    tmp[t] = v;
    __syncthreads();
    for (int off = 1; off < 256; off <<= 1) {
        int add = (t >= off) ? tmp[t - off] : 0;
        __syncthreads();
        tmp[t] += add;
        __syncthreads();
    }
    partial[i] = tmp[t] - v;
    if (t == 255) bsum[blockIdx.x] = tmp[255];
}

__global__ __launch_bounds__(512) void scan2_kernel(const int* __restrict__ bsum,
                                                    int* __restrict__ boff) {
    __shared__ int tmp[512];
    int t = threadIdx.x;
    int v = (t < NB) ? bsum[t] : 0;
    tmp[t] = v;
    __syncthreads();
    for (int off = 1; off < 512; off <<= 1) {
        int add = (t >= off) ? tmp[t - off] : 0;
        __syncthreads();
        tmp[t] += add;
        __syncthreads();
    }
    boff[t] = tmp[t] - v;
}

__global__ __launch_bounds__(256) void fill_kernel(const int* __restrict__ ei,
                                                   const float* __restrict__ x,
                                                   const float* __restrict__ ea,
                                                   const int* __restrict__ partial,
                                                   const int* __restrict__ boff,
                                                   int* __restrict__ cnt2,
                                                   int* __restrict__ rowp,
                                                   short* __restrict__ in_csr) {
    int e = blockIdx.x * 256 + threadIdx.x;
    if (e < NE) {
        int r = ei[e];
        int c = ei[NE + e];
        int p = partial[r] + boff[r >> 8] + atomicAdd(&cnt2[r], 1);
        rowp[p] = r;
        s16x8 v = {0, 0, 0, 0, 0, 0, 0, 0};
        v[0] = f2bf(x[2 * c]);  v[1] = f2bf(x[2 * c + 1]);
        v[2] = f2bf(ea[2 * e]); v[3] = f2bf(ea[2 * e + 1]);
        *(s16x8*)&in_csr[(size_t)p * 8] = v;
    }
}

// ---------------------------------------------------------------------------
// zero aggb rows of isolated (deg==0) nodes; everything else is overwritten.
// ---------------------------------------------------------------------------
__global__ __launch_bounds__(256) void zero_empty_kernel(const int* __restrict__ deg,
                                                         short* __restrict__ aggb) {
    int n = blockIdx.x * 256 + threadIdx.x;
    if (n < NN && deg[n] == 0) {
        s16x8 z = {0, 0, 0, 0, 0, 0, 0, 0};
        short* dst = aggb + (size_t)n * 128;
#pragma unroll
        for (int j = 0; j < 16; ++j) *(s16x8*)&dst[j * 8] = z;
    }
}

// ---------------------------------------------------------------------------
// Weight prep (unchanged from R13): frag-major W2aF/W2bF, W1aT [64][32]
// (K=4 zero-padded), W1bT [128][64].
// ---------------------------------------------------------------------------
__global__ __launch_bounds__(256) void prep_kernel(const float* __restrict__ W2a,
                                                   const float* __restrict__ W2b,
                                                   const float* __restrict__ W1a,
                                                   const float* __restrict__ W1b,
                                                   short* __restrict__ W2aF,
                                                   short* __restrict__ W2bF,
                                                   short* __restrict__ W1aT,
                                                   short* __restrict__ W1bT) {
    int idx = blockIdx.x * 256 + threadIdx.x;
    if (idx < 16 * 5 * 512) {                     // W2aF: 40960
        int j = idx & 7;
        int lane = (idx >> 3) & 63;
        int t2 = idx >> 9;
        int ks = t2 % 5, nb = t2 / 5;
        int n = nb * 16 + (lane & 15);
        int k = ks * 32 + (lane >> 4) * 8 + j;    // < 160
        float v = 0.f;
        if (k < 128)       v = W2a[(2 + k) * 256 + n];
        else if (k == 128) v = W2a[0 * 256 + n];
        else if (k == 129) v = W2a[1 * 256 + n];
        else if (k == 130) v = W2a[130 * 256 + n];
        else if (k == 131) v = W2a[131 * 256 + n];
        W2aF[idx] = f2bf(v);
    }
    if (idx < 32 * 8 * 512) {                     // W2bF: 131072
        int j = idx & 7;
        int lane = (idx >> 3) & 63;
        int t2 = idx >> 9;
        int ks = t2 & 7, nb = t2 >> 3;
        int n = nb * 16 + (lane & 15);
        int k = ks * 32 + (lane >> 4) * 8 + j;    // < 256
        W2bF[idx] = f2bf(W2b[k * 512 + n]);
    }
    if (idx < 64 * 32) {
        int n = idx >> 5, k = idx & 31;
        W1aT[idx] = (k < 4) ? f2bf(W1a[k * 64 + n]) : (short)0;
    }
    if (idx < 128 * 64) {
        int n = idx >> 6, k = idx & 63;
        W1bT[idx] = f2bf(W1b[k * 128 + n]);
    }
}

// ---------------------------------------------------------------------------
// Edge fused (R14 structure; agg now bf16, base computed inline).
// ---------------------------------------------------------------------------
__global__ __launch_bounds__(256) void edge_fused_kernel(
    const short* __restrict__ in_csr, const int* __restrict__ rowp,
    const short* __restrict__ W1aT, const short* __restrict__ W1bT,
    const float* __restrict__ b1a, const float* __restrict__ b1b,
    const int* __restrict__ partial, const int* __restrict__ boff,
    const int* __restrict__ deg,
    short* __restrict__ aggb, float* __restrict__ pstart,
    float* __restrict__ pend, int* __restrict__ eid)
{
    __shared__ short in[64 * 48];     // [edge][k] K=32 (cols 4..31 zero)
    __shared__ short t1[64 * 72];     // [edge][64]
    __shared__ short hbf[64 * 136];   // [edge][128] bf16
    __shared__ int   rows[64];
    __shared__ float midlo[128], midhi[128];
    const int tid = threadIdx.x;
    const int p0 = blockIdx.x * 64;

    // ---- stage
    if (tid < 64) {
        *(s16x8*)&in[tid * 48] = *(const s16x8*)&in_csr[(size_t)(p0 + tid) * 8];
        rows[tid] = rowp[p0 + tid];
    } else {
        int t2 = tid - 64;            // 0..191: zero cols 8..31 of all rows
        int r = t2 / 3, ch = t2 % 3;
        s16x8 z = {0, 0, 0, 0, 0, 0, 0, 0};
        *(s16x8*)&in[r * 48 + 8 + ch * 8] = z;
    }
    __syncthreads();

    const int lane = tid & 63, nw = tid >> 6;
    const int l15 = lane & 15, lk = lane >> 4;

    // ---- L1 swapped: A=W1a(t1col,k) B=in(edge,k); wave nw -> t1cols nw*16..+16
    f32x4 a1[4];
#pragma unroll
    for (int bf = 0; bf < 4; ++bf) a1[bf] = (f32x4){0.f, 0.f, 0.f, 0.f};
    {
        s16x8 wA = *(const s16x8*)&W1aT[(nw * 16 + l15) * 32 + lk * 8];
#pragma unroll
        for (int bf = 0; bf < 4; ++bf) {
            s16x8 bI = *(const s16x8*)&in[(bf * 16 + l15) * 48 + lk * 8];
            a1[bf] = __builtin_amdgcn_mfma_f32_16x16x32_bf16(wA, bI, a1[bf], 0, 0, 0);
        }
    }
    // ---- epilogue1: thread owns t1[edge=bf*16+l15][t1col0..+3], t1col0=nw*16+lk*4
    {
        f32x4 bias = *(const f32x4*)&b1a[nw * 16 + lk * 4];
#pragma unroll
        for (int bf = 0; bf < 4; ++bf) {
            s16x4 pk;
#pragma unroll
            for (int j = 0; j < 4; ++j)
                pk[j] = f2bf(fmaxf(a1[bf][j] + bias[j], 0.f));
            *(s16x4*)&t1[(bf * 16 + l15) * 72 + nw * 16 + lk * 4] = pk;
        }
    }
    __syncthreads();

    // ---- L2 swapped: A=W1b(outcol,k=64) B=t1(edge,k); wave nw -> outcols nw*32..+32
    f32x4 a2[2][4];
#pragma unroll
    for (int af = 0; af < 2; ++af)
#pragma unroll
        for (int bf = 0; bf < 4; ++bf) a2[af][bf] = (f32x4){0.f, 0.f, 0.f, 0.f};

#pragma unroll
    for (int ks = 0; ks < 2; ++ks) {
        s16x8 w[2], b[4];
#pragma unroll
        for (int af = 0; af < 2; ++af)
            w[af] = *(const s16x8*)&W1bT[((nw * 2 + af) * 16 + l15) * 64 + ks * 32 + lk * 8];
#pragma unroll
        for (int bf = 0; bf < 4; ++bf)
            b[bf] = *(const s16x8*)&t1[(bf * 16 + l15) * 72 + ks * 32 + lk * 8];
#pragma unroll
        for (int af = 0; af < 2; ++af)
#pragma unroll
            for (int bf = 0; bf < 4; ++bf)
                a2[af][bf] = __builtin_amdgcn_mfma_f32_16x16x32_bf16(
                    w[af], b[bf], a2[af][bf], 0, 0, 0);
    }
    // ---- epilogue2: thread owns hbf[edge=bf*16+l15][outcol0..+3]
#pragma unroll
    for (int af = 0; af < 2; ++af) {
        int oc0 = (nw * 2 + af) * 16 + lk * 4;
        f32x4 bias = *(const f32x4*)&b1b[oc0];
#pragma unroll
        for (int bf = 0; bf < 4; ++bf) {
            s16x4 pk;
#pragma unroll
            for (int j = 0; j < 4; ++j)
                pk[j] = f2bf(a2[af][bf][j] + bias[j]);
            *(s16x4*)&hbf[(bf * 16 + l15) * 136 + oc0] = pk;
        }
    }
    __syncthreads();

    // ---- segmented reduce: two 32-slot halves, all 256 threads
    {
        const int half = tid >> 7;
        const int c = tid & 127;
        const int slo = half * 32, shi = slo + 32;
        float sum = 0.f;
        int cur = rows[slo];
        bool first = true;
        for (int i = slo; i < shi; ++i) {
            sum += bf2f((unsigned short)hbf[i * 136 + c]);
            bool segend = (i == shi - 1) || (rows[i + 1] != cur);
            if (segend) {
                bool crossMid  = (half == 0) && (i == 31) && (rows[32] == cur);
                bool fromLower = (half == 1) && first && (rows[31] == cur);
                if (crossMid) {
                    midlo[c] = sum;
                } else if (fromLower) {
                    midhi[c] = sum;
                } else {
                    int bs = partial[cur] + boff[cur >> 8];
                    int d = deg[cur];
                    bool sh = bs >= p0, eh = bs + d <= p0 + 64;
                    if (sh && eh)      aggb[(size_t)cur * 128 + c] = f2bf(sum / (float)d);
                    else if (sh)       pend[(size_t)blockIdx.x * 128 + c] = sum;
                    else if (eh)       pstart[(size_t)blockIdx.x * 128 + c] = sum;
                }
                sum = 0.f;
                first = false;
                if (i < shi - 1) cur = rows[i + 1];
            }
        }
    }
    __syncthreads();
    // ---- mid-merge: the (single) node crossing slot 31/32
    if (tid < 128 && rows[31] == rows[32]) {
        int c = tid, cur = rows[32];
        float s = midlo[c] + midhi[c];
        int bs = partial[cur] + boff[cur >> 8];
        int d = deg[cur];
        bool sh = bs >= p0, eh = bs + d <= p0 + 64;
        if (sh && eh)      aggb[(size_t)cur * 128 + c] = f2bf(s / (float)d);
        else if (sh)       pend[(size_t)blockIdx.x * 128 + c] = s;
        else if (eh)       pstart[(size_t)blockIdx.x * 128 + c] = s;
    }
    if (tid == 0) {
        int nlast = rows[63];
        int bs = partial[nlast] + boff[nlast >> 8];
        eid[blockIdx.x] = (bs + deg[nlast] > p0 + 64) ? nlast : -1;
    }
}

// ---------------------------------------------------------------------------
// Boundary fixup: node straddling blocks k/k+1 -> aggb = (pend_k+pstart_k1)/d
// ---------------------------------------------------------------------------
__global__ __launch_bounds__(128) void fixup_kernel(
    const float* __restrict__ pend, const float* __restrict__ pstart,
    const int* __restrict__ eid, const int* __restrict__ deg,
    short* __restrict__ aggb)
{
    int k = blockIdx.x;
    int n = eid[k];
    if (n < 0) return;
    int c = threadIdx.x;
    float s = pend[(size_t)k * 128 + c] + pstart[(size_t)(k + 1) * 128 + c];
    aggb[(size_t)n * 128 + c] = f2bf(s / (float)deg[n]);
}

// ---------------------------------------------------------------------------
// Node MFMA v3: staging reads bf16 aggb directly (pure b128 copies, no cvt).
// Otherwise identical to proven R13 v2 (swapped operands, frag-major weights,
// LDS union, vectorized epilogues).
// ---------------------------------------------------------------------------
__global__ __launch_bounds__(512, 4) void node_mfma_kernel(
    const float* __restrict__ x, const float* __restrict__ u,
    const int* __restrict__ batch,
    const short* __restrict__ aggb,
    const short* __restrict__ W2aF, const short* __restrict__ W2bF,
    const float* __restrict__ b2a, const float* __restrict__ b2b,
    float* __restrict__ out)
{
    __shared__ short lds[64 * 256];   // union: zb[64][192] then tb[64][256]
    const int tid = threadIdx.x;
    const int node0 = blockIdx.x * 64;

    // ---- stage aggb -> zb chunks 0..15 (b128 copy, chunk-XOR swizzle)
#pragma unroll
    for (int it = 0; it < 2; ++it) {
        int idx = it * 512 + tid;         // 1024 = 64 rows * 16 chunks
        int r = idx >> 4, ch = idx & 15;
        int node = node0 + r;
        s16x8 v = {0, 0, 0, 0, 0, 0, 0, 0};
        if (node < NN) v = *(const s16x8*)&aggb[(size_t)node * 128 + ch * 8];
        int sw = (ch & ~7) | ((ch ^ r) & 7);
        *(s16x8*)&lds[r * 192 + sw * 8] = v;
    }
    if (tid < 64) {
        int r = tid, node = node0 + r;
        s16x8 p = {0, 0, 0, 0, 0, 0, 0, 0};
        if (node < NN) {
            p[0] = f2bf(x[node * 2]); p[1] = f2bf(x[node * 2 + 1]);
            int b = batch[node];
            p[2] = f2bf(u[b * 2]); p[3] = f2bf(u[b * 2 + 1]);
        }
        int sw = 16 | (r & 7);
        *(s16x8*)&lds[r * 192 + sw * 8] = p;
    } else if (tid < 256) {
        int t2 = tid - 64;
        int r = t2 & 63;
        int ch = 17 + (t2 >> 6);
        int sw = (ch & ~7) | ((ch ^ r) & 7);
        s16x8 zz = {0, 0, 0, 0, 0, 0, 0, 0};
        *(s16x8*)&lds[r * 192 + sw * 8] = zz;
    }
    __syncthreads();

    const int lane = tid & 63, nw = tid >> 6;
    const int l15 = lane & 15, lk = lane >> 4;

    f32x4 acc1[4][2];
#pragma unroll
    for (int mf = 0; mf < 4; ++mf)
#pragma unroll
        for (int nf = 0; nf < 2; ++nf)
            acc1[mf][nf] = (f32x4){0.f, 0.f, 0.f, 0.f};

#pragma unroll
    for (int ks = 0; ks < 5; ++ks) {
        s16x8 a[4], w[2];
        int cb = ks * 4 + lk;
#pragma unroll
        for (int mf = 0; mf < 4; ++mf) {
            int r = mf * 16 + l15;
            int sw = (cb & ~7) | ((cb ^ r) & 7);
            a[mf] = *(const s16x8*)&lds[r * 192 + sw * 8];
        }
#pragma unroll
        for (int nf = 0; nf < 2; ++nf)
            w[nf] = *(const s16x8*)&W2aF[((((nw * 2 + nf) * 5) + ks) * 64 + lane) * 8];
#pragma unroll
        for (int mf = 0; mf < 4; ++mf)
#pragma unroll
            for (int nf = 0; nf < 2; ++nf)
                acc1[mf][nf] = __builtin_amdgcn_mfma_f32_16x16x32_bf16(
                    w[nf], a[mf], acc1[mf][nf], 0, 0, 0);
    }
    __syncthreads();

#pragma unroll
    for (int nf = 0; nf < 2; ++nf) {
        int n0 = nw * 32 + nf * 16 + lk * 4;
        f32x4 bias = *(const f32x4*)&b2a[n0];
        int ch = n0 >> 3, off = n0 & 7;
#pragma unroll
        for (int mf = 0; mf < 4; ++mf) {
            int m = mf * 16 + l15;
            s16x4 pk;
#pragma unroll
            for (int j = 0; j < 4; ++j)
                pk[j] = f2bf(fmaxf(acc1[mf][nf][j] + bias[j], 0.f));
            int sw = (ch & ~7) | ((ch ^ m) & 7);
            *(s16x4*)&lds[m * 256 + sw * 8 + off] = pk;
        }
    }
    __syncthreads();

    f32x4 acc2[4][4];
#pragma unroll
    for (int mf = 0; mf < 4; ++mf)
#pragma unroll
        for (int nf = 0; nf < 4; ++nf)
            acc2[mf][nf] = (f32x4){0.f, 0.f, 0.f, 0.f};

#pragma unroll
    for (int ks = 0; ks < 8; ++ks) {
        s16x8 b[4], w[4];
        int cb = ks * 4 + lk;
#pragma unroll
        for (int mf = 0; mf < 4; ++mf) {
            int r = mf * 16 + l15;
            int sw = (cb & ~7) | ((cb ^ r) & 7);
            b[mf] = *(const s16x8*)&lds[r * 256 + sw * 8];
        }
#pragma unroll
        for (int nf = 0; nf < 4; ++nf)
            w[nf] = *(const s16x8*)&W2bF[((((nw * 4 + nf) * 8) + ks) * 64 + lane) * 8];
#pragma unroll
        for (int mf = 0; mf < 4; ++mf)
#pragma unroll
            for (int nf = 0; nf < 4; ++nf)
                acc2[mf][nf] = __builtin_amdgcn_mfma_f32_16x16x32_bf16(
                    w[nf], b[mf], acc2[mf][nf], 0, 0, 0);
    }

#pragma unroll
    for (int nf = 0; nf < 4; ++nf) {
        int n0 = nw * 64 + nf * 16 + lk * 4;
        f32x4 bias = *(const f32x4*)&b2b[n0];
#pragma unroll
        for (int mf = 0; mf < 4; ++mf) {
            int node = node0 + mf * 16 + l15;
            if (node < NN) {
                f32x4 o = acc2[mf][nf] + bias;
                *(f32x4*)&out[(size_t)node * 512 + n0] = o;
            }
        }
    }
}

extern "C" void kernel_launch(void* const* d_in, const int* in_sizes, int n_in,
                              void* d_out, int out_size, void* d_ws, size_t ws_size,
                              hipStream_t stream) {
    const float* x          = (const float*)d_in[0];
    const int*   edge_index = (const int*)d_in[1];
    const float* edge_attr  = (const float*)d_in[2];
    const float* u          = (const float*)d_in[3];
    const int*   batch      = (const int*)d_in[4];
    const float* W1a        = (const float*)d_in[5];
    const float* b1a        = (const float*)d_in[6];
    const float* W1b        = (const float*)d_in[7];
    const float* b1b        = (const float*)d_in[8];
    const float* W2a        = (const float*)d_in[9];
    const float* b2a        = (const float*)d_in[10];
    const float* W2b        = (const float*)d_in[11];
    const float* b2b        = (const float*)d_in[12];
    float* out = (float*)d_out;

    // workspace layout
    short* aggb   = (short*)d_ws;                        // [NN,128] bf16
    short* W2aF   = aggb + (size_t)NN * 128;             // [16*5*512] bf16
    short* W2bF   = W2aF + 16 * 5 * 512;                 // [32*8*512] bf16
    short* W1aT   = W2bF + 32 * 8 * 512;                 // [64,32]   bf16
    short* W1bT   = W1aT + 64 * 32;                      // [128,64]  bf16
    int*   deg    = (int*)(W1bT + 128 * 64);             // [NP]
    int*   cnt2   = deg + NP;                            // [NP] (memset with deg)
    int*   partial= cnt2 + NP;                           // [NP]
    int*   bsum   = partial + NP;                        // [512]
    int*   boff   = bsum + 512;                          // [512]
    int*   rowp   = boff + 512;                          // [NE]
    int*   eid    = rowp + NE;                           // [NBE]
    float* pstart = (float*)(eid + NBE);                 // [NBE,128]
    float* pend   = pstart + (size_t)NBE * 128;          // [NBE,128]
    short* in_csr = (short*)(pend + (size_t)NBE * 128);  // [NE,8] bf16

    hipMemsetAsync(deg, 0, 2 * NP * sizeof(int), stream);

    prep_kernel <<<512, 256, 0, stream>>>(W2a, W2b, W1a, W1b,
                                          W2aF, W2bF, W1aT, W1bT);
    hist_kernel <<<(NE + 255) / 256, 256, 0, stream>>>(edge_index, deg);
    scan1_kernel<<<NB, 256, 0, stream>>>(deg, partial, bsum);
    scan2_kernel<<<1, 512, 0, stream>>>(bsum, boff);
    fill_kernel <<<(NE + 255) / 256, 256, 0, stream>>>(edge_index, x, edge_attr,
                                                       partial, boff, cnt2,
                                                       rowp, in_csr);
    zero_empty_kernel<<<NB, 256, 0, stream>>>(deg, aggb);

    edge_fused_kernel<<<NBE, 256, 0, stream>>>(
        in_csr, rowp, W1aT, W1bT, b1a, b1b,
        partial, boff, deg, aggb, pstart, pend, eid);

    fixup_kernel<<<NBE - 1, 128, 0, stream>>>(pend, pstart, eid, deg, aggb);

    node_mfma_kernel<<<(NN + 63) / 64, 512, 0, stream>>>(
        x, u, batch, aggb, W2aF, W2bF, b2a, b2b, out);
}

// Round 16
// 231.051 us; speedup vs baseline: 1.4554x; 1.0575x over previous
//
#include <hip/hip_runtime.h>

#define NN 100000
#define NE 600000
#define NP 100096   // 391*256, padded node count
#define NB 391
#define NBE 9375    // NE/64 edge blocks

typedef float v4    __attribute__((ext_vector_type(4)));
typedef float f32x4 __attribute__((ext_vector_type(4)));
typedef short s16x4 __attribute__((ext_vector_type(4)));
typedef short s16x8 __attribute__((ext_vector_type(8)));

__device__ __forceinline__ short f2bf(float f) {
    unsigned u = __float_as_uint(f);
    u = (u + 0x7fffu + ((u >> 16) & 1u)) >> 16;
    return (short)u;
}
__device__ __forceinline__ float bf2f(unsigned short v) {
    return __uint_as_float(((unsigned)v) << 16);
}

// ---------------------------------------------------------------------------
// hist + weight-prep fused (prep's 131k-thread range fits in hist's grid;
// independent work, concurrent). Frag-major W2aF/W2bF; W1aT K=4->32 pad;
// W1bT [128][64].
// ---------------------------------------------------------------------------
__global__ __launch_bounds__(256) void hist_prep_kernel(
    const int* __restrict__ ei, int* __restrict__ deg,
    const float* __restrict__ W2a, const float* __restrict__ W2b,
    const float* __restrict__ W1a, const float* __restrict__ W1b,
    short* __restrict__ W2aF, short* __restrict__ W2bF,
    short* __restrict__ W1aT, short* __restrict__ W1bT)
{
    int idx = blockIdx.x * 256 + threadIdx.x;
    if (idx < NE) atomicAdd(&deg[ei[idx]], 1);

    if (idx < 16 * 5 * 512) {                     // W2aF: 40960
        int j = idx & 7;
        int lane = (idx >> 3) & 63;
        int t2 = idx >> 9;
        int ks = t2 % 5, nb = t2 / 5;
        int n = nb * 16 + (lane & 15);
        int k = ks * 32 + (lane >> 4) * 8 + j;    // < 160
        float v = 0.f;
        if (k < 128)       v = W2a[(2 + k) * 256 + n];
        else if (k == 128) v = W2a[0 * 256 + n];
        else if (k == 129) v = W2a[1 * 256 + n];
        else if (k == 130) v = W2a[130 * 256 + n];
        else if (k == 131) v = W2a[131 * 256 + n];
        W2aF[idx] = f2bf(v);
    }
    if (idx < 32 * 8 * 512) {                     // W2bF: 131072
        int j = idx & 7;
        int lane = (idx >> 3) & 63;
        int t2 = idx >> 9;
        int ks = t2 & 7, nb = t2 >> 3;
        int n = nb * 16 + (lane & 15);
        int k = ks * 32 + (lane >> 4) * 8 + j;    // < 256
        W2bF[idx] = f2bf(W2b[k * 512 + n]);
    }
    if (idx < 64 * 32) {
        int n = idx >> 5, k = idx & 31;
        W1aT[idx] = (k < 4) ? f2bf(W1a[k * 64 + n]) : (short)0;
    }
    if (idx < 128 * 64) {
        int n = idx >> 6, k = idx & 63;
        W1bT[idx] = f2bf(W1b[k * 128 + n]);
    }
}

__global__ __launch_bounds__(256) void scan1_kernel(const int* __restrict__ deg,
                                                    int* __restrict__ partial,
                                                    int* __restrict__ bsum) {
    __shared__ int tmp[256];
    int t = threadIdx.x;
    int i = blockIdx.x * 256 + t;
    int v = deg[i];
    tmp[t] = v;
    __syncthreads();
    for (int off = 1; off < 256; off <<= 1) {
        int add = (t >= off) ? tmp[t - off] : 0;
        __syncthreads();
        tmp[t] += add;
        __syncthreads();
    }
    partial[i] = tmp[t] - v;
    if (t == 255) bsum[blockIdx.x] = tmp[255];
}

__global__ __launch_bounds__(512) void scan2_kernel(const int* __restrict__ bsum,
                                                    int* __restrict__ boff) {
    __shared__ int tmp[512];
    int t = threadIdx.x;
    int v = (t < NB) ? bsum[t] : 0;
    tmp[t] = v;
    __syncthreads();
    for (int off = 1; off < 512; off <<= 1) {
        int add = (t >= off) ? tmp[t - off] : 0;
        __syncthreads();
        tmp[t] += add;
        __syncthreads();
    }
    boff[t] = tmp[t] - v;
}

__global__ __launch_bounds__(256) void fill_kernel(const int* __restrict__ ei,
                                                   const float* __restrict__ x,
                                                   const float* __restrict__ ea,
                                                   const int* __restrict__ partial,
                                                   const int* __restrict__ boff,
                                                   int* __restrict__ cnt2,
                                                   int* __restrict__ rowp,
                                                   short* __restrict__ in_csr) {
    int e = blockIdx.x * 256 + threadIdx.x;
    if (e < NE) {
        int r = ei[e];
        int c = ei[NE + e];
        int p = partial[r] + boff[r >> 8] + atomicAdd(&cnt2[r], 1);
        rowp[p] = r;
        s16x8 v = {0, 0, 0, 0, 0, 0, 0, 0};
        v[0] = f2bf(x[2 * c]);  v[1] = f2bf(x[2 * c + 1]);
        v[2] = f2bf(ea[2 * e]); v[3] = f2bf(ea[2 * e + 1]);
        *(s16x8*)&in_csr[(size_t)p * 8] = v;
    }
}

// ---------------------------------------------------------------------------
// Edge fused (R15 structure, eid removed): interior nodes -> aggb bf16;
// boundary partial sums (fp32) -> pend[blk]/pstart[blk], consumed by node.
// ---------------------------------------------------------------------------
__global__ __launch_bounds__(256) void edge_fused_kernel(
    const short* __restrict__ in_csr, const int* __restrict__ rowp,
    const short* __restrict__ W1aT, const short* __restrict__ W1bT,
    const float* __restrict__ b1a, const float* __restrict__ b1b,
    const int* __restrict__ partial, const int* __restrict__ boff,
    const int* __restrict__ deg,
    short* __restrict__ aggb, float* __restrict__ pstart,
    float* __restrict__ pend)
{
    __shared__ short in[64 * 48];     // [edge][k] K=32 (cols 4..31 zero)
    __shared__ short t1[64 * 72];     // [edge][64]
    __shared__ short hbf[64 * 136];   // [edge][128] bf16
    __shared__ int   rows[64];
    __shared__ float midlo[128], midhi[128];
    const int tid = threadIdx.x;
    const int p0 = blockIdx.x * 64;

    // ---- stage
    if (tid < 64) {
        *(s16x8*)&in[tid * 48] = *(const s16x8*)&in_csr[(size_t)(p0 + tid) * 8];
        rows[tid] = rowp[p0 + tid];
    } else {
        int t2 = tid - 64;            // 0..191: zero cols 8..31 of all rows
        int r = t2 / 3, ch = t2 % 3;
        s16x8 z = {0, 0, 0, 0, 0, 0, 0, 0};
        *(s16x8*)&in[r * 48 + 8 + ch * 8] = z;
    }
    __syncthreads();

    const int lane = tid & 63, nw = tid >> 6;
    const int l15 = lane & 15, lk = lane >> 4;

    // ---- L1 swapped: A=W1a(t1col,k) B=in(edge,k); wave nw -> t1cols nw*16..+16
    f32x4 a1[4];
#pragma unroll
    for (int bf = 0; bf < 4; ++bf) a1[bf] = (f32x4){0.f, 0.f, 0.f, 0.f};
    {
        s16x8 wA = *(const s16x8*)&W1aT[(nw * 16 + l15) * 32 + lk * 8];
#pragma unroll
        for (int bf = 0; bf < 4; ++bf) {
            s16x8 bI = *(const s16x8*)&in[(bf * 16 + l15) * 48 + lk * 8];
            a1[bf] = __builtin_amdgcn_mfma_f32_16x16x32_bf16(wA, bI, a1[bf], 0, 0, 0);
        }
    }
    // ---- epilogue1
    {
        f32x4 bias = *(const f32x4*)&b1a[nw * 16 + lk * 4];
#pragma unroll
        for (int bf = 0; bf < 4; ++bf) {
            s16x4 pk;
#pragma unroll
            for (int j = 0; j < 4; ++j)
                pk[j] = f2bf(fmaxf(a1[bf][j] + bias[j], 0.f));
            *(s16x4*)&t1[(bf * 16 + l15) * 72 + nw * 16 + lk * 4] = pk;
        }
    }
    __syncthreads();

    // ---- L2 swapped: wave nw -> outcols nw*32..+32
    f32x4 a2[2][4];
#pragma unroll
    for (int af = 0; af < 2; ++af)
#pragma unroll
        for (int bf = 0; bf < 4; ++bf) a2[af][bf] = (f32x4){0.f, 0.f, 0.f, 0.f};

#pragma unroll
    for (int ks = 0; ks < 2; ++ks) {
        s16x8 w[2], b[4];
#pragma unroll
        for (int af = 0; af < 2; ++af)
            w[af] = *(const s16x8*)&W1bT[((nw * 2 + af) * 16 + l15) * 64 + ks * 32 + lk * 8];
#pragma unroll
        for (int bf = 0; bf < 4; ++bf)
            b[bf] = *(const s16x8*)&t1[(bf * 16 + l15) * 72 + ks * 32 + lk * 8];
#pragma unroll
        for (int af = 0; af < 2; ++af)
#pragma unroll
            for (int bf = 0; bf < 4; ++bf)
                a2[af][bf] = __builtin_amdgcn_mfma_f32_16x16x32_bf16(
                    w[af], b[bf], a2[af][bf], 0, 0, 0);
    }
    // ---- epilogue2
#pragma unroll
    for (int af = 0; af < 2; ++af) {
        int oc0 = (nw * 2 + af) * 16 + lk * 4;
        f32x4 bias = *(const f32x4*)&b1b[oc0];
#pragma unroll
        for (int bf = 0; bf < 4; ++bf) {
            s16x4 pk;
#pragma unroll
            for (int j = 0; j < 4; ++j)
                pk[j] = f2bf(a2[af][bf][j] + bias[j]);
            *(s16x4*)&hbf[(bf * 16 + l15) * 136 + oc0] = pk;
        }
    }
    __syncthreads();

    // ---- segmented reduce: two 32-slot halves, all 256 threads
    {
        const int half = tid >> 7;
        const int c = tid & 127;
        const int slo = half * 32, shi = slo + 32;
        float sum = 0.f;
        int cur = rows[slo];
        bool first = true;
        for (int i = slo; i < shi; ++i) {
            sum += bf2f((unsigned short)hbf[i * 136 + c]);
            bool segend = (i == shi - 1) || (rows[i + 1] != cur);
            if (segend) {
                bool crossMid  = (half == 0) && (i == 31) && (rows[32] == cur);
                bool fromLower = (half == 1) && first && (rows[31] == cur);
                if (crossMid) {
                    midlo[c] = sum;
                } else if (fromLower) {
                    midhi[c] = sum;
                } else {
                    int bs = partial[cur] + boff[cur >> 8];
                    int d = deg[cur];
                    bool sh = bs >= p0, eh = bs + d <= p0 + 64;
                    if (sh && eh)      aggb[(size_t)cur * 128 + c] = f2bf(sum / (float)d);
                    else if (sh)       pend[(size_t)blockIdx.x * 128 + c] = sum;
                    else if (eh)       pstart[(size_t)blockIdx.x * 128 + c] = sum;
                }
                sum = 0.f;
                first = false;
                if (i < shi - 1) cur = rows[i + 1];
            }
        }
    }
    __syncthreads();
    // ---- mid-merge: the (single) node crossing slot 31/32
    if (tid < 128 && rows[31] == rows[32]) {
        int c = tid, cur = rows[32];
        float s = midlo[c] + midhi[c];
        int bs = partial[cur] + boff[cur >> 8];
        int d = deg[cur];
        bool sh = bs >= p0, eh = bs + d <= p0 + 64;
        if (sh && eh)      aggb[(size_t)cur * 128 + c] = f2bf(s / (float)d);
        else if (sh)       pend[(size_t)blockIdx.x * 128 + c] = s;
        else if (eh)       pstart[(size_t)blockIdx.x * 128 + c] = s;
    }
}

// ---------------------------------------------------------------------------
// Node MFMA v4: staging handles all three agg sources per row:
//   mode 0: deg==0 or padding -> zeros        (replaces zero_empty kernel)
//   mode 1: interior          -> aggb bf16 b128 copy
//   mode 2: boundary          -> (pend[k]+pstart[k+1])/d fp32  (replaces fixup)
// Core GEMM identical to proven R13 v2.
// ---------------------------------------------------------------------------
__global__ __launch_bounds__(512, 4) void node_mfma_kernel(
    const float* __restrict__ x, const float* __restrict__ u,
    const int* __restrict__ batch,
    const short* __restrict__ aggb,
    const int* __restrict__ deg, const int* __restrict__ partial,
    const int* __restrict__ boff,
    const float* __restrict__ pstart, const float* __restrict__ pend,
    const short* __restrict__ W2aF, const short* __restrict__ W2bF,
    const float* __restrict__ b2a, const float* __restrict__ b2b,
    float* __restrict__ out)
{
    __shared__ short lds[64 * 256];   // union: zb[64][192] then tb[64][256]
    __shared__ int   rmode[64];
    __shared__ float rinv[64];
    __shared__ int   rk[64];
    const int tid = threadIdx.x;
    const int node0 = blockIdx.x * 64;

    // ---- per-row descriptors
    if (tid < 64) {
        int node = node0 + tid;
        int mode = 0, k = 0;
        float inv = 0.f;
        if (node < NN) {
            int d = deg[node];
            if (d > 0) {
                int bs = partial[node] + boff[node >> 8];
                k = bs >> 6;
                mode = ((bs & 63) + d > 64) ? 2 : 1;
                inv = 1.0f / (float)d;
            }
        }
        rmode[tid] = mode; rinv[tid] = inv; rk[tid] = k;
    }
    __syncthreads();

    // ---- stage agg -> zb chunks 0..15 (chunk-XOR swizzle)
#pragma unroll
    for (int it = 0; it < 2; ++it) {
        int idx = it * 512 + tid;         // 1024 = 64 rows * 16 chunks
        int r = idx >> 4, ch = idx & 15;
        int node = node0 + r;
        int mode = rmode[r];
        s16x8 v = {0, 0, 0, 0, 0, 0, 0, 0};
        if (mode == 1) {
            v = *(const s16x8*)&aggb[(size_t)node * 128 + ch * 8];
        } else if (mode == 2) {
            float inv = rinv[r];
            int k = rk[r];
            const float* pe = &pend[(size_t)k * 128 + ch * 8];
            const float* ps = &pstart[(size_t)(k + 1) * 128 + ch * 8];
#pragma unroll
            for (int j = 0; j < 8; ++j)
                v[j] = f2bf((pe[j] + ps[j]) * inv);
        }
        int sw = (ch & ~7) | ((ch ^ r) & 7);
        *(s16x8*)&lds[r * 192 + sw * 8] = v;
    }
    if (tid < 64) {
        int r = tid, node = node0 + r;
        s16x8 p = {0, 0, 0, 0, 0, 0, 0, 0};
        if (node < NN) {
            p[0] = f2bf(x[node * 2]); p[1] = f2bf(x[node * 2 + 1]);
            int b = batch[node];
            p[2] = f2bf(u[b * 2]); p[3] = f2bf(u[b * 2 + 1]);
        }
        int sw = 16 | (r & 7);
        *(s16x8*)&lds[r * 192 + sw * 8] = p;
    } else if (tid < 256) {
        int t2 = tid - 64;
        int r = t2 & 63;
        int ch = 17 + (t2 >> 6);
        int sw = (ch & ~7) | ((ch ^ r) & 7);
        s16x8 zz = {0, 0, 0, 0, 0, 0, 0, 0};
        *(s16x8*)&lds[r * 192 + sw * 8] = zz;
    }
    __syncthreads();

    const int lane = tid & 63, nw = tid >> 6;
    const int l15 = lane & 15, lk = lane >> 4;

    f32x4 acc1[4][2];
#pragma unroll
    for (int mf = 0; mf < 4; ++mf)
#pragma unroll
        for (int nf = 0; nf < 2; ++nf)
            acc1[mf][nf] = (f32x4){0.f, 0.f, 0.f, 0.f};

#pragma unroll
    for (int ks = 0; ks < 5; ++ks) {
        s16x8 a[4], w[2];
        int cb = ks * 4 + lk;
#pragma unroll
        for (int mf = 0; mf < 4; ++mf) {
            int r = mf * 16 + l15;
            int sw = (cb & ~7) | ((cb ^ r) & 7);
            a[mf] = *(const s16x8*)&lds[r * 192 + sw * 8];
        }
#pragma unroll
        for (int nf = 0; nf < 2; ++nf)
            w[nf] = *(const s16x8*)&W2aF[((((nw * 2 + nf) * 5) + ks) * 64 + lane) * 8];
#pragma unroll
        for (int mf = 0; mf < 4; ++mf)
#pragma unroll
            for (int nf = 0; nf < 2; ++nf)
                acc1[mf][nf] = __builtin_amdgcn_mfma_f32_16x16x32_bf16(
                    w[nf], a[mf], acc1[mf][nf], 0, 0, 0);
    }
    __syncthreads();

#pragma unroll
    for (int nf = 0; nf < 2; ++nf) {
        int n0 = nw * 32 + nf * 16 + lk * 4;
        f32x4 bias = *(const f32x4*)&b2a[n0];
        int ch = n0 >> 3, off = n0 & 7;
#pragma unroll
        for (int mf = 0; mf < 4; ++mf) {
            int m = mf * 16 + l15;
            s16x4 pk;
#pragma unroll
            for (int j = 0; j < 4; ++j)
                pk[j] = f2bf(fmaxf(acc1[mf][nf][j] + bias[j], 0.f));
            int sw = (ch & ~7) | ((ch ^ m) & 7);
            *(s16x4*)&lds[m * 256 + sw * 8 + off] = pk;
        }
    }
    __syncthreads();

    f32x4 acc2[4][4];
#pragma unroll
    for (int mf = 0; mf < 4; ++mf)
#pragma unroll
        for (int nf = 0; nf < 4; ++nf)
            acc2[mf][nf] = (f32x4){0.f, 0.f, 0.f, 0.f};

#pragma unroll
    for (int ks = 0; ks < 8; ++ks) {
        s16x8 b[4], w[4];
        int cb = ks * 4 + lk;
#pragma unroll
        for (int mf = 0; mf < 4; ++mf) {
            int r = mf * 16 + l15;
            int sw = (cb & ~7) | ((cb ^ r) & 7);
            b[mf] = *(const s16x8*)&lds[r * 256 + sw * 8];
        }
#pragma unroll
        for (int nf = 0; nf < 4; ++nf)
            w[nf] = *(const s16x8*)&W2bF[((((nw * 4 + nf) * 8) + ks) * 64 + lane) * 8];
#pragma unroll
        for (int mf = 0; mf < 4; ++mf)
#pragma unroll
            for (int nf = 0; nf < 4; ++nf)
                acc2[mf][nf] = __builtin_amdgcn_mfma_f32_16x16x32_bf16(
                    w[nf], b[mf], acc2[mf][nf], 0, 0, 0);
    }

#pragma unroll
    for (int nf = 0; nf < 4; ++nf) {
        int n0 = nw * 64 + nf * 16 + lk * 4;
        f32x4 bias = *(const f32x4*)&b2b[n0];
#pragma unroll
        for (int mf = 0; mf < 4; ++mf) {
            int node = node0 + mf * 16 + l15;
            if (node < NN) {
                f32x4 o = acc2[mf][nf] + bias;
                *(f32x4*)&out[(size_t)node * 512 + n0] = o;
            }
        }
    }
}

extern "C" void kernel_launch(void* const* d_in, const int* in_sizes, int n_in,
                              void* d_out, int out_size, void* d_ws, size_t ws_size,
                              hipStream_t stream) {
    const float* x          = (const float*)d_in[0];
    const int*   edge_index = (const int*)d_in[1];
    const float* edge_attr  = (const float*)d_in[2];
    const float* u          = (const float*)d_in[3];
    const int*   batch      = (const int*)d_in[4];
    const float* W1a        = (const float*)d_in[5];
    const float* b1a        = (const float*)d_in[6];
    const float* W1b        = (const float*)d_in[7];
    const float* b1b        = (const float*)d_in[8];
    const float* W2a        = (const float*)d_in[9];
    const float* b2a        = (const float*)d_in[10];
    const float* W2b        = (const float*)d_in[11];
    const float* b2b        = (const float*)d_in[12];
    float* out = (float*)d_out;

    // workspace layout
    short* aggb   = (short*)d_ws;                        // [NN,128] bf16
    short* W2aF   = aggb + (size_t)NN * 128;             // [16*5*512] bf16
    short* W2bF   = W2aF + 16 * 5 * 512;                 // [32*8*512] bf16
    short* W1aT   = W2bF + 32 * 8 * 512;                 // [64,32]   bf16
    short* W1bT   = W1aT + 64 * 32;                      // [128,64]  bf16
    int*   deg    = (int*)(W1bT + 128 * 64);             // [NP]
    int*   cnt2   = deg + NP;                            // [NP] (memset with deg)
    int*   partial= cnt2 + NP;                           // [NP]
    int*   bsum   = partial + NP;                        // [512]
    int*   boff   = bsum + 512;                          // [512]
    int*   rowp   = boff + 512;                          // [NE]
    float* pstart = (float*)(rowp + NE);                 // [NBE,128]
    float* pend   = pstart + (size_t)NBE * 128;          // [NBE,128]
    short* in_csr = (short*)(pend + (size_t)NBE * 128);  // [NE,8] bf16

    hipMemsetAsync(deg, 0, 2 * NP * sizeof(int), stream);

    hist_prep_kernel<<<(NE + 255) / 256, 256, 0, stream>>>(
        edge_index, deg, W2a, W2b, W1a, W1b, W2aF, W2bF, W1aT, W1bT);
    scan1_kernel<<<NB, 256, 0, stream>>>(deg, partial, bsum);
    scan2_kernel<<<1, 512, 0, stream>>>(bsum, boff);
    fill_kernel <<<(NE + 255) / 256, 256, 0, stream>>>(edge_index, x, edge_attr,
                                                       partial, boff, cnt2,
                                                       rowp, in_csr);

    edge_fused_kernel<<<NBE, 256, 0, stream>>>(
        in_csr, rowp, W1aT, W1bT, b1a, b1b,
        partial, boff, deg, aggb, pstart, pend);

    node_mfma_kernel<<<(NN + 63) / 64, 512, 0, stream>>>(
        x, u, batch, aggb, deg, partial, boff, pstart, pend,
        W2aF, W2bF, b2a, b2b, out);
}

// Round 17
// 217.417 us; speedup vs baseline: 1.5466x; 1.0627x over previous
//
#include <hip/hip_runtime.h>

#define NN 100000
#define NE 600000
#define NP 100096   // 391*256, padded node count
#define NB 391
#define NBE 9375    // NE/64 edge blocks

typedef float v4    __attribute__((ext_vector_type(4)));
typedef float f32x4 __attribute__((ext_vector_type(4)));
typedef short s16x4 __attribute__((ext_vector_type(4)));
typedef short s16x8 __attribute__((ext_vector_type(8)));

__device__ __forceinline__ short f2bf(float f) {
    unsigned u = __float_as_uint(f);
    u = (u + 0x7fffu + ((u >> 16) & 1u)) >> 16;
    return (short)u;
}
__device__ __forceinline__ float bf2f(unsigned short v) {
    return __uint_as_float(((unsigned)v) << 16);
}

// ---------------------------------------------------------------------------
// hist + weight-prep fused (unchanged from R16).
// ---------------------------------------------------------------------------
__global__ __launch_bounds__(256) void hist_prep_kernel(
    const int* __restrict__ ei, int* __restrict__ deg,
    const float* __restrict__ W2a, const float* __restrict__ W2b,
    const float* __restrict__ W1a, const float* __restrict__ W1b,
    short* __restrict__ W2aF, short* __restrict__ W2bF,
    short* __restrict__ W1aT, short* __restrict__ W1bT)
{
    int idx = blockIdx.x * 256 + threadIdx.x;
    if (idx < NE) atomicAdd(&deg[ei[idx]], 1);

    if (idx < 16 * 5 * 512) {                     // W2aF: 40960
        int j = idx & 7;
        int lane = (idx >> 3) & 63;
        int t2 = idx >> 9;
        int ks = t2 % 5, nb = t2 / 5;
        int n = nb * 16 + (lane & 15);
        int k = ks * 32 + (lane >> 4) * 8 + j;    // < 160
        float v = 0.f;
        if (k < 128)       v = W2a[(2 + k) * 256 + n];
        else if (k == 128) v = W2a[0 * 256 + n];
        else if (k == 129) v = W2a[1 * 256 + n];
        else if (k == 130) v = W2a[130 * 256 + n];
        else if (k == 131) v = W2a[131 * 256 + n];
        W2aF[idx] = f2bf(v);
    }
    if (idx < 32 * 8 * 512) {                     // W2bF: 131072
        int j = idx & 7;
        int lane = (idx >> 3) & 63;
        int t2 = idx >> 9;
        int ks = t2 & 7, nb = t2 >> 3;
        int n = nb * 16 + (lane & 15);
        int k = ks * 32 + (lane >> 4) * 8 + j;    // < 256
        W2bF[idx] = f2bf(W2b[k * 512 + n]);
    }
    if (idx < 64 * 32) {
        int n = idx >> 5, k = idx & 31;
        W1aT[idx] = (k < 4) ? f2bf(W1a[k * 64 + n]) : (short)0;
    }
    if (idx < 128 * 64) {
        int n = idx >> 6, k = idx & 63;
        W1bT[idx] = f2bf(W1b[k * 128 + n]);
    }
}

__global__ __launch_bounds__(256) void scan1_kernel(const int* __restrict__ deg,
                                                    int* __restrict__ partial,
                                                    int* __restrict__ bsum) {
    __shared__ int tmp[256];
    int t = threadIdx.x;
    int i = blockIdx.x * 256 + t;
    int v = deg[i];
    tmp[t] = v;
    __syncthreads();
    for (int off = 1; off < 256; off <<= 1) {
        int add = (t >= off) ? tmp[t - off] : 0;
        __syncthreads();
        tmp[t] += add;
        __syncthreads();
    }
    partial[i] = tmp[t] - v;
    if (t == 255) bsum[blockIdx.x] = tmp[255];
}

__global__ __launch_bounds__(512) void scan2_kernel(const int* __restrict__ bsum,
                                                    int* __restrict__ boff) {
    __shared__ int tmp[512];
    int t = threadIdx.x;
    int v = (t < NB) ? bsum[t] : 0;
    tmp[t] = v;
    __syncthreads();
    for (int off = 1; off < 512; off <<= 1) {
        int add = (t >= off) ? tmp[t - off] : 0;
        __syncthreads();
        tmp[t] += add;
        __syncthreads();
    }
    boff[t] = tmp[t] - v;
}

__global__ __launch_bounds__(256) void fill_kernel(const int* __restrict__ ei,
                                                   const float* __restrict__ x,
                                                   const float* __restrict__ ea,
                                                   const int* __restrict__ partial,
                                                   const int* __restrict__ boff,
                                                   int* __restrict__ cnt2,
                                                   int* __restrict__ rowp,
                                                   short* __restrict__ in_csr) {
    int e = blockIdx.x * 256 + threadIdx.x;
    if (e < NE) {
        int r = ei[e];
        int c = ei[NE + e];
        int p = partial[r] + boff[r >> 8] + atomicAdd(&cnt2[r], 1);
        rowp[p] = r;
        s16x8 v = {0, 0, 0, 0, 0, 0, 0, 0};
        v[0] = f2bf(x[2 * c]);  v[1] = f2bf(x[2 * c + 1]);
        v[2] = f2bf(ea[2 * e]); v[3] = f2bf(ea[2 * e + 1]);
        *(s16x8*)&in_csr[(size_t)p * 8] = v;
    }
}

// ---------------------------------------------------------------------------
// Edge fused v3: LDS pool union {in[64*48] | t1[64*72]} -> hbf[64*136].
// Block LDS ~18.7KB (was ~34KB) + __launch_bounds__(256,8) VGPR<=64:
// occupancy 16 -> up to 32 waves/CU for this latency-bound kernel.
// One extra barrier (L2 t1-reads must drain before hbf overwrites the pool).
// ---------------------------------------------------------------------------
__global__ __launch_bounds__(256, 8) void edge_fused_kernel(
    const short* __restrict__ in_csr, const int* __restrict__ rowp,
    const short* __restrict__ W1aT, const short* __restrict__ W1bT,
    const float* __restrict__ b1a, const float* __restrict__ b1b,
    const int* __restrict__ partial, const int* __restrict__ boff,
    const int* __restrict__ deg,
    short* __restrict__ aggb, float* __restrict__ pstart,
    float* __restrict__ pend)
{
    __shared__ short pool[64 * 136];  // union: in[64*48]+t1[64*72] then hbf
    __shared__ int   rows[64];
    __shared__ float midlo[128], midhi[128];
    short* in  = pool;                // [edge][48], cols 4..31 zero
    short* t1  = pool + 64 * 48;      // [edge][72]  (7680 <= 8704 shorts)
    short* hbf = pool;                // [edge][136] after t1 drained
    const int tid = threadIdx.x;
    const int p0 = blockIdx.x * 64;

    // ---- stage
    if (tid < 64) {
        *(s16x8*)&in[tid * 48] = *(const s16x8*)&in_csr[(size_t)(p0 + tid) * 8];
        rows[tid] = rowp[p0 + tid];
    } else {
        int t2 = tid - 64;            // 0..191: zero cols 8..31 of all rows
        int r = t2 / 3, ch = t2 % 3;
        s16x8 z = {0, 0, 0, 0, 0, 0, 0, 0};
        *(s16x8*)&in[r * 48 + 8 + ch * 8] = z;
    }
    __syncthreads();

    const int lane = tid & 63, nw = tid >> 6;
    const int l15 = lane & 15, lk = lane >> 4;

    // ---- L1 swapped: A=W1a(t1col,k) B=in(edge,k); wave nw -> t1cols nw*16..+16
    f32x4 a1[4];
#pragma unroll
    for (int bf = 0; bf < 4; ++bf) a1[bf] = (f32x4){0.f, 0.f, 0.f, 0.f};
    {
        s16x8 wA = *(const s16x8*)&W1aT[(nw * 16 + l15) * 32 + lk * 8];
#pragma unroll
        for (int bf = 0; bf < 4; ++bf) {
            s16x8 bI = *(const s16x8*)&in[(bf * 16 + l15) * 48 + lk * 8];
            a1[bf] = __builtin_amdgcn_mfma_f32_16x16x32_bf16(wA, bI, a1[bf], 0, 0, 0);
        }
    }
    // ---- epilogue1 (t1 region disjoint from in reads above; no hazard)
    {
        f32x4 bias = *(const f32x4*)&b1a[nw * 16 + lk * 4];
#pragma unroll
        for (int bf = 0; bf < 4; ++bf) {
            s16x4 pk;
#pragma unroll
            for (int j = 0; j < 4; ++j)
                pk[j] = f2bf(fmaxf(a1[bf][j] + bias[j], 0.f));
            *(s16x4*)&t1[(bf * 16 + l15) * 72 + nw * 16 + lk * 4] = pk;
        }
    }
    __syncthreads();

    // ---- L2 swapped: wave nw -> outcols nw*32..+32
    f32x4 a2[2][4];
#pragma unroll
    for (int af = 0; af < 2; ++af)
#pragma unroll
        for (int bf = 0; bf < 4; ++bf) a2[af][bf] = (f32x4){0.f, 0.f, 0.f, 0.f};

#pragma unroll
    for (int ks = 0; ks < 2; ++ks) {
        s16x8 w[2], b[4];
#pragma unroll
        for (int af = 0; af < 2; ++af)
            w[af] = *(const s16x8*)&W1bT[((nw * 2 + af) * 16 + l15) * 64 + ks * 32 + lk * 8];
#pragma unroll
        for (int bf = 0; bf < 4; ++bf)
            b[bf] = *(const s16x8*)&t1[(bf * 16 + l15) * 72 + ks * 32 + lk * 8];
#pragma unroll
        for (int af = 0; af < 2; ++af)
#pragma unroll
            for (int bf = 0; bf < 4; ++bf)
                a2[af][bf] = __builtin_amdgcn_mfma_f32_16x16x32_bf16(
                    w[af], b[bf], a2[af][bf], 0, 0, 0);
    }
    __syncthreads();   // drain all t1 reads before hbf overwrites pool

    // ---- epilogue2 -> hbf (pool reuse)
#pragma unroll
    for (int af = 0; af < 2; ++af) {
        int oc0 = (nw * 2 + af) * 16 + lk * 4;
        f32x4 bias = *(const f32x4*)&b1b[oc0];
#pragma unroll
        for (int bf = 0; bf < 4; ++bf) {
            s16x4 pk;
#pragma unroll
            for (int j = 0; j < 4; ++j)
                pk[j] = f2bf(a2[af][bf][j] + bias[j]);
            *(s16x4*)&hbf[(bf * 16 + l15) * 136 + oc0] = pk;
        }
    }
    __syncthreads();

    // ---- segmented reduce: two 32-slot halves, all 256 threads
    {
        const int half = tid >> 7;
        const int c = tid & 127;
        const int slo = half * 32, shi = slo + 32;
        float sum = 0.f;
        int cur = rows[slo];
        bool first = true;
        for (int i = slo; i < shi; ++i) {
            sum += bf2f((unsigned short)hbf[i * 136 + c]);
            bool segend = (i == shi - 1) || (rows[i + 1] != cur);
            if (segend) {
                bool crossMid  = (half == 0) && (i == 31) && (rows[32] == cur);
                bool fromLower = (half == 1) && first && (rows[31] == cur);
                if (crossMid) {
                    midlo[c] = sum;
                } else if (fromLower) {
                    midhi[c] = sum;
                } else {
                    int bs = partial[cur] + boff[cur >> 8];
                    int d = deg[cur];
                    bool sh = bs >= p0, eh = bs + d <= p0 + 64;
                    if (sh && eh)      aggb[(size_t)cur * 128 + c] = f2bf(sum / (float)d);
                    else if (sh)       pend[(size_t)blockIdx.x * 128 + c] = sum;
                    else if (eh)       pstart[(size_t)blockIdx.x * 128 + c] = sum;
                }
                sum = 0.f;
                first = false;
                if (i < shi - 1) cur = rows[i + 1];
            }
        }
    }
    __syncthreads();
    // ---- mid-merge: the (single) node crossing slot 31/32
    if (tid < 128 && rows[31] == rows[32]) {
        int c = tid, cur = rows[32];
        float s = midlo[c] + midhi[c];
        int bs = partial[cur] + boff[cur >> 8];
        int d = deg[cur];
        bool sh = bs >= p0, eh = bs + d <= p0 + 64;
        if (sh && eh)      aggb[(size_t)cur * 128 + c] = f2bf(s / (float)d);
        else if (sh)       pend[(size_t)blockIdx.x * 128 + c] = s;
        else if (eh)       pstart[(size_t)blockIdx.x * 128 + c] = s;
    }
}

// ---------------------------------------------------------------------------
// Node MFMA v4 (unchanged from R16): staging handles zero/interior/boundary
// rows; core GEMM is the proven R13 v2 structure.
// ---------------------------------------------------------------------------
__global__ __launch_bounds__(512, 4) void node_mfma_kernel(
    const float* __restrict__ x, const float* __restrict__ u,
    const int* __restrict__ batch,
    const short* __restrict__ aggb,
    const int* __restrict__ deg, const int* __restrict__ partial,
    const int* __restrict__ boff,
    const float* __restrict__ pstart, const float* __restrict__ pend,
    const short* __restrict__ W2aF, const short* __restrict__ W2bF,
    const float* __restrict__ b2a, const float* __restrict__ b2b,
    float* __restrict__ out)
{
    __shared__ short lds[64 * 256];   // union: zb[64][192] then tb[64][256]
    __shared__ int   rmode[64];
    __shared__ float rinv[64];
    __shared__ int   rk[64];
    const int tid = threadIdx.x;
    const int node0 = blockIdx.x * 64;

    if (tid < 64) {
        int node = node0 + tid;
        int mode = 0, k = 0;
        float inv = 0.f;
        if (node < NN) {
            int d = deg[node];
            if (d > 0) {
                int bs = partial[node] + boff[node >> 8];
                k = bs >> 6;
                mode = ((bs & 63) + d > 64) ? 2 : 1;
                inv = 1.0f / (float)d;
            }
        }
        rmode[tid] = mode; rinv[tid] = inv; rk[tid] = k;
    }
    __syncthreads();

#pragma unroll
    for (int it = 0; it < 2; ++it) {
        int idx = it * 512 + tid;         // 1024 = 64 rows * 16 chunks
        int r = idx >> 4, ch = idx & 15;
        int node = node0 + r;
        int mode = rmode[r];
        s16x8 v = {0, 0, 0, 0, 0, 0, 0, 0};
        if (mode == 1) {
            v = *(const s16x8*)&aggb[(size_t)node * 128 + ch * 8];
        } else if (mode == 2) {
            float inv = rinv[r];
            int k = rk[r];
            const float* pe = &pend[(size_t)k * 128 + ch * 8];
            const float* ps = &pstart[(size_t)(k + 1) * 128 + ch * 8];
#pragma unroll
            for (int j = 0; j < 8; ++j)
                v[j] = f2bf((pe[j] + ps[j]) * inv);
        }
        int sw = (ch & ~7) | ((ch ^ r) & 7);
        *(s16x8*)&lds[r * 192 + sw * 8] = v;
    }
    if (tid < 64) {
        int r = tid, node = node0 + r;
        s16x8 p = {0, 0, 0, 0, 0, 0, 0, 0};
        if (node < NN) {
            p[0] = f2bf(x[node * 2]); p[1] = f2bf(x[node * 2 + 1]);
            int b = batch[node];
            p[2] = f2bf(u[b * 2]); p[3] = f2bf(u[b * 2 + 1]);
        }
        int sw = 16 | (r & 7);
        *(s16x8*)&lds[r * 192 + sw * 8] = p;
    } else if (tid < 256) {
        int t2 = tid - 64;
        int r = t2 & 63;
        int ch = 17 + (t2 >> 6);
        int sw = (ch & ~7) | ((ch ^ r) & 7);
        s16x8 zz = {0, 0, 0, 0, 0, 0, 0, 0};
        *(s16x8*)&lds[r * 192 + sw * 8] = zz;
    }
    __syncthreads();

    const int lane = tid & 63, nw = tid >> 6;
    const int l15 = lane & 15, lk = lane >> 4;

    f32x4 acc1[4][2];
#pragma unroll
    for (int mf = 0; mf < 4; ++mf)
#pragma unroll
        for (int nf = 0; nf < 2; ++nf)
            acc1[mf][nf] = (f32x4){0.f, 0.f, 0.f, 0.f};

#pragma unroll
    for (int ks = 0; ks < 5; ++ks) {
        s16x8 a[4], w[2];
        int cb = ks * 4 + lk;
#pragma unroll
        for (int mf = 0; mf < 4; ++mf) {
            int r = mf * 16 + l15;
            int sw = (cb & ~7) | ((cb ^ r) & 7);
            a[mf] = *(const s16x8*)&lds[r * 192 + sw * 8];
        }
#pragma unroll
        for (int nf = 0; nf < 2; ++nf)
            w[nf] = *(const s16x8*)&W2aF[((((nw * 2 + nf) * 5) + ks) * 64 + lane) * 8];
#pragma unroll
        for (int mf = 0; mf < 4; ++mf)
#pragma unroll
            for (int nf = 0; nf < 2; ++nf)
                acc1[mf][nf] = __builtin_amdgcn_mfma_f32_16x16x32_bf16(
                    w[nf], a[mf], acc1[mf][nf], 0, 0, 0);
    }
    __syncthreads();

#pragma unroll
    for (int nf = 0; nf < 2; ++nf) {
        int n0 = nw * 32 + nf * 16 + lk * 4;
        f32x4 bias = *(const f32x4*)&b2a[n0];
        int ch = n0 >> 3, off = n0 & 7;
#pragma unroll
        for (int mf = 0; mf < 4; ++mf) {
            int m = mf * 16 + l15;
            s16x4 pk;
#pragma unroll
            for (int j = 0; j < 4; ++j)
                pk[j] = f2bf(fmaxf(acc1[mf][nf][j] + bias[j], 0.f));
            int sw = (ch & ~7) | ((ch ^ m) & 7);
            *(s16x4*)&lds[m * 256 + sw * 8 + off] = pk;
        }
    }
    __syncthreads();

    f32x4 acc2[4][4];
#pragma unroll
    for (int mf = 0; mf < 4; ++mf)
#pragma unroll
        for (int nf = 0; nf < 4; ++nf)
            acc2[mf][nf] = (f32x4){0.f, 0.f, 0.f, 0.f};

#pragma unroll
    for (int ks = 0; ks < 8; ++ks) {
        s16x8 b[4], w[4];
        int cb = ks * 4 + lk;
#pragma unroll
        for (int mf = 0; mf < 4; ++mf) {
            int r = mf * 16 + l15;
            int sw = (cb & ~7) | ((cb ^ r) & 7);
            b[mf] = *(const s16x8*)&lds[r * 256 + sw * 8];
        }
#pragma unroll
        for (int nf = 0; nf < 4; ++nf)
            w[nf] = *(const s16x8*)&W2bF[((((nw * 4 + nf) * 8) + ks) * 64 + lane) * 8];
#pragma unroll
        for (int mf = 0; mf < 4; ++mf)
#pragma unroll
            for (int nf = 0; nf < 4; ++nf)
                acc2[mf][nf] = __builtin_amdgcn_mfma_f32_16x16x32_bf16(
                    w[nf], b[mf], acc2[mf][nf], 0, 0, 0);
    }

#pragma unroll
    for (int nf = 0; nf < 4; ++nf) {
        int n0 = nw * 64 + nf * 16 + lk * 4;
        f32x4 bias = *(const f32x4*)&b2b[n0];
#pragma unroll
        for (int mf = 0; mf < 4; ++mf) {
            int node = node0 + mf * 16 + l15;
            if (node < NN) {
                f32x4 o = acc2[mf][nf] + bias;
                *(f32x4*)&out[(size_t)node * 512 + n0] = o;
            }
        }
    }
}

extern "C" void kernel_launch(void* const* d_in, const int* in_sizes, int n_in,
                              void* d_out, int out_size, void* d_ws, size_t ws_size,
                              hipStream_t stream) {
    const float* x          = (const float*)d_in[0];
    const int*   edge_index = (const int*)d_in[1];
    const float* edge_attr  = (const float*)d_in[2];
    const float* u          = (const float*)d_in[3];
    const int*   batch      = (const int*)d_in[4];
    const float* W1a        = (const float*)d_in[5];
    const float* b1a        = (const float*)d_in[6];
    const float* W1b        = (const float*)d_in[7];
    const float* b1b        = (const float*)d_in[8];
    const float* W2a        = (const float*)d_in[9];
    const float* b2a        = (const float*)d_in[10];
    const float* W2b        = (const float*)d_in[11];
    const float* b2b        = (const float*)d_in[12];
    float* out = (float*)d_out;

    // workspace layout
    short* aggb   = (short*)d_ws;                        // [NN,128] bf16
    short* W2aF   = aggb + (size_t)NN * 128;             // [16*5*512] bf16
    short* W2bF   = W2aF + 16 * 5 * 512;                 // [32*8*512] bf16
    short* W1aT   = W2bF + 32 * 8 * 512;                 // [64,32]   bf16
    short* W1bT   = W1aT + 64 * 32;                      // [128,64]  bf16
    int*   deg    = (int*)(W1bT + 128 * 64);             // [NP]
    int*   cnt2   = deg + NP;                            // [NP] (memset with deg)
    int*   partial= cnt2 + NP;                           // [NP]
    int*   bsum   = partial + NP;                        // [512]
    int*   boff   = bsum + 512;                          // [512]
    int*   rowp   = boff + 512;                          // [NE]
    float* pstart = (float*)(rowp + NE);                 // [NBE,128]
    float* pend   = pstart + (size_t)NBE * 128;          // [NBE,128]
    short* in_csr = (short*)(pend + (size_t)NBE * 128);  // [NE,8] bf16

    hipMemsetAsync(deg, 0, 2 * NP * sizeof(int), stream);

    hist_prep_kernel<<<(NE + 255) / 256, 256, 0, stream>>>(
        edge_index, deg, W2a, W2b, W1a, W1b, W2aF, W2bF, W1aT, W1bT);
    scan1_kernel<<<NB, 256, 0, stream>>>(deg, partial, bsum);
    scan2_kernel<<<1, 512, 0, stream>>>(bsum, boff);
    fill_kernel <<<(NE + 255) / 256, 256, 0, stream>>>(edge_index, x, edge_attr,
                                                       partial, boff, cnt2,
                                                       rowp, in_csr);

    edge_fused_kernel<<<NBE, 256, 0, stream>>>(
        in_csr, rowp, W1aT, W1bT, b1a, b1b,
        partial, boff, deg, aggb, pstart, pend);

    node_mfma_kernel<<<(NN + 63) / 64, 512, 0, stream>>>(
        x, u, batch, aggb, deg, partial, boff, pstart, pend,
        W2aF, W2bF, b2a, b2b, out);
}

// Round 18
// 211.125 us; speedup vs baseline: 1.5927x; 1.0298x over previous
//
#include <hip/hip_runtime.h>

#define NN 100000
#define NE 600000
#define NP 100096   // 391*256, padded node count
#define NB 391
#define NBE 9375    // NE/64 edge blocks

typedef float v4    __attribute__((ext_vector_type(4)));
typedef float f32x4 __attribute__((ext_vector_type(4)));
typedef short s16x4 __attribute__((ext_vector_type(4)));
typedef short s16x8 __attribute__((ext_vector_type(8)));

__device__ __forceinline__ short f2bf(float f) {
    unsigned u = __float_as_uint(f);
    u = (u + 0x7fffu + ((u >> 16) & 1u)) >> 16;
    return (short)u;
}
__device__ __forceinline__ float bf2f(unsigned short v) {
    return __uint_as_float(((unsigned)v) << 16);
}

// ---------------------------------------------------------------------------
// hist + weight-prep fused (unchanged).
// ---------------------------------------------------------------------------
__global__ __launch_bounds__(256) void hist_prep_kernel(
    const int* __restrict__ ei, int* __restrict__ deg,
    const float* __restrict__ W2a, const float* __restrict__ W2b,
    const float* __restrict__ W1a, const float* __restrict__ W1b,
    short* __restrict__ W2aF, short* __restrict__ W2bF,
    short* __restrict__ W1aT, short* __restrict__ W1bT)
{
    int idx = blockIdx.x * 256 + threadIdx.x;
    if (idx < NE) atomicAdd(&deg[ei[idx]], 1);

    if (idx < 16 * 5 * 512) {                     // W2aF: 40960
        int j = idx & 7;
        int lane = (idx >> 3) & 63;
        int t2 = idx >> 9;
        int ks = t2 % 5, nb = t2 / 5;
        int n = nb * 16 + (lane & 15);
        int k = ks * 32 + (lane >> 4) * 8 + j;    // < 160
        float v = 0.f;
        if (k < 128)       v = W2a[(2 + k) * 256 + n];
        else if (k == 128) v = W2a[0 * 256 + n];
        else if (k == 129) v = W2a[1 * 256 + n];
        else if (k == 130) v = W2a[130 * 256 + n];
        else if (k == 131) v = W2a[131 * 256 + n];
        W2aF[idx] = f2bf(v);
    }
    if (idx < 32 * 8 * 512) {                     // W2bF: 131072
        int j = idx & 7;
        int lane = (idx >> 3) & 63;
        int t2 = idx >> 9;
        int ks = t2 & 7, nb = t2 >> 3;
        int n = nb * 16 + (lane & 15);
        int k = ks * 32 + (lane >> 4) * 8 + j;    // < 256
        W2bF[idx] = f2bf(W2b[k * 512 + n]);
    }
    if (idx < 64 * 32) {
        int n = idx >> 5, k = idx & 31;
        W1aT[idx] = (k < 4) ? f2bf(W1a[k * 64 + n]) : (short)0;
    }
    if (idx < 128 * 64) {
        int n = idx >> 6, k = idx & 63;
        W1bT[idx] = f2bf(W1b[k * 128 + n]);
    }
}

__global__ __launch_bounds__(256) void scan1_kernel(const int* __restrict__ deg,
                                                    int* __restrict__ partial,
                                                    int* __restrict__ bsum) {
    __shared__ int tmp[256];
    int t = threadIdx.x;
    int i = blockIdx.x * 256 + t;
    int v = deg[i];
    tmp[t] = v;
    __syncthreads();
    for (int off = 1; off < 256; off <<= 1) {
        int add = (t >= off) ? tmp[t - off] : 0;
        __syncthreads();
        tmp[t] += add;
        __syncthreads();
    }
    partial[i] = tmp[t] - v;
    if (t == 255) bsum[blockIdx.x] = tmp[255];
}

__global__ __launch_bounds__(512) void scan2_kernel(const int* __restrict__ bsum,
                                                    int* __restrict__ boff) {
    __shared__ int tmp[512];
    int t = threadIdx.x;
    int v = (t < NB) ? bsum[t] : 0;
    tmp[t] = v;
    __syncthreads();
    for (int off = 1; off < 512; off <<= 1) {
        int add = (t >= off) ? tmp[t - off] : 0;
        __syncthreads();
        tmp[t] += add;
        __syncthreads();
    }
    boff[t] = tmp[t] - v;
}

__global__ __launch_bounds__(256) void fill_kernel(const int* __restrict__ ei,
                                                   const float* __restrict__ x,
                                                   const float* __restrict__ ea,
                                                   const int* __restrict__ partial,
                                                   const int* __restrict__ boff,
                                                   int* __restrict__ cnt2,
                                                   int* __restrict__ rowp,
                                                   short* __restrict__ in_csr) {
    int e = blockIdx.x * 256 + threadIdx.x;
    if (e < NE) {
        int r = ei[e];
        int c = ei[NE + e];
        int p = partial[r] + boff[r >> 8] + atomicAdd(&cnt2[r], 1);
        rowp[p] = r;
        s16x8 v = {0, 0, 0, 0, 0, 0, 0, 0};
        v[0] = f2bf(x[2 * c]);  v[1] = f2bf(x[2 * c + 1]);
        v[2] = f2bf(ea[2 * e]); v[3] = f2bf(ea[2 * e + 1]);
        *(s16x8*)&in_csr[(size_t)p * 8] = v;
    }
}

// ---------------------------------------------------------------------------
// Edge fused v4: NO input LDS staging — the L1 B-fragment is
//   lk==0 ? 16B direct load from in_csr[row*8] : zero   (k>=8 cols are pad).
// Removes the stage phase + 2 barriers (5 -> 3). LDS pool: t1[64*72] then
// hbf[64*136] (union, ~17.4KB). __launch_bounds__(256,8) as R17.
// ---------------------------------------------------------------------------
__global__ __launch_bounds__(256, 8) void edge_fused_kernel(
    const short* __restrict__ in_csr, const int* __restrict__ rowp,
    const short* __restrict__ W1aT, const short* __restrict__ W1bT,
    const float* __restrict__ b1a, const float* __restrict__ b1b,
    const int* __restrict__ partial, const int* __restrict__ boff,
    const int* __restrict__ deg,
    short* __restrict__ aggb, float* __restrict__ pstart,
    float* __restrict__ pend)
{
    __shared__ short pool[64 * 136];  // union: t1[64*72] then hbf[64*136]
    __shared__ int   rows[64];
    __shared__ float midlo[128], midhi[128];
    short* t1  = pool;                // [edge][72]
    short* hbf = pool;                // [edge][136] after L2 reads drain
    const int tid = threadIdx.x;
    const int p0 = blockIdx.x * 64;

    if (tid < 64) rows[tid] = rowp[p0 + tid];   // covered by epilogue1 barrier

    const int lane = tid & 63, nw = tid >> 6;
    const int l15 = lane & 15, lk = lane >> 4;

    // ---- L1 swapped: A=W1a(t1col,k) B=in(edge,k) direct from global
    f32x4 a1[4];
#pragma unroll
    for (int bf = 0; bf < 4; ++bf) a1[bf] = (f32x4){0.f, 0.f, 0.f, 0.f};
    {
        s16x8 wA = *(const s16x8*)&W1aT[(nw * 16 + l15) * 32 + lk * 8];
        s16x8 zz = {0, 0, 0, 0, 0, 0, 0, 0};
#pragma unroll
        for (int bf = 0; bf < 4; ++bf) {
            s16x8 bI = zz;
            if (lk == 0)
                bI = *(const s16x8*)&in_csr[(size_t)(p0 + bf * 16 + l15) * 8];
            a1[bf] = __builtin_amdgcn_mfma_f32_16x16x32_bf16(wA, bI, a1[bf], 0, 0, 0);
        }
    }
    // ---- epilogue1 -> t1
    {
        f32x4 bias = *(const f32x4*)&b1a[nw * 16 + lk * 4];
#pragma unroll
        for (int bf = 0; bf < 4; ++bf) {
            s16x4 pk;
#pragma unroll
            for (int j = 0; j < 4; ++j)
                pk[j] = f2bf(fmaxf(a1[bf][j] + bias[j], 0.f));
            *(s16x4*)&t1[(bf * 16 + l15) * 72 + nw * 16 + lk * 4] = pk;
        }
    }
    __syncthreads();

    // ---- L2 swapped: wave nw -> outcols nw*32..+32
    f32x4 a2[2][4];
#pragma unroll
    for (int af = 0; af < 2; ++af)
#pragma unroll
        for (int bf = 0; bf < 4; ++bf) a2[af][bf] = (f32x4){0.f, 0.f, 0.f, 0.f};

#pragma unroll
    for (int ks = 0; ks < 2; ++ks) {
        s16x8 w[2], b[4];
#pragma unroll
        for (int af = 0; af < 2; ++af)
            w[af] = *(const s16x8*)&W1bT[((nw * 2 + af) * 16 + l15) * 64 + ks * 32 + lk * 8];
#pragma unroll
        for (int bf = 0; bf < 4; ++bf)
            b[bf] = *(const s16x8*)&t1[(bf * 16 + l15) * 72 + ks * 32 + lk * 8];
#pragma unroll
        for (int af = 0; af < 2; ++af)
#pragma unroll
            for (int bf = 0; bf < 4; ++bf)
                a2[af][bf] = __builtin_amdgcn_mfma_f32_16x16x32_bf16(
                    w[af], b[bf], a2[af][bf], 0, 0, 0);
    }
    __syncthreads();   // drain t1 reads before hbf overwrites pool

    // ---- epilogue2 -> hbf (pool reuse)
#pragma unroll
    for (int af = 0; af < 2; ++af) {
        int oc0 = (nw * 2 + af) * 16 + lk * 4;
        f32x4 bias = *(const f32x4*)&b1b[oc0];
#pragma unroll
        for (int bf = 0; bf < 4; ++bf) {
            s16x4 pk;
#pragma unroll
            for (int j = 0; j < 4; ++j)
                pk[j] = f2bf(a2[af][bf][j] + bias[j]);
            *(s16x4*)&hbf[(bf * 16 + l15) * 136 + oc0] = pk;
        }
    }
    __syncthreads();

    // ---- segmented reduce: two 32-slot halves, all 256 threads
    {
        const int half = tid >> 7;
        const int c = tid & 127;
        const int slo = half * 32, shi = slo + 32;
        float sum = 0.f;
        int cur = rows[slo];
        bool first = true;
        for (int i = slo; i < shi; ++i) {
            sum += bf2f((unsigned short)hbf[i * 136 + c]);
            bool segend = (i == shi - 1) || (rows[i + 1] != cur);
            if (segend) {
                bool crossMid  = (half == 0) && (i == 31) && (rows[32] == cur);
                bool fromLower = (half == 1) && first && (rows[31] == cur);
                if (crossMid) {
                    midlo[c] = sum;
                } else if (fromLower) {
                    midhi[c] = sum;
                } else {
                    int bs = partial[cur] + boff[cur >> 8];
                    int d = deg[cur];
                    bool sh = bs >= p0, eh = bs + d <= p0 + 64;
                    if (sh && eh)      aggb[(size_t)cur * 128 + c] = f2bf(sum / (float)d);
                    else if (sh)       pend[(size_t)blockIdx.x * 128 + c] = sum;
                    else if (eh)       pstart[(size_t)blockIdx.x * 128 + c] = sum;
                }
                sum = 0.f;
                first = false;
                if (i < shi - 1) cur = rows[i + 1];
            }
        }
    }
    __syncthreads();
    // ---- mid-merge: the (single) node crossing slot 31/32
    if (tid < 128 && rows[31] == rows[32]) {
        int c = tid, cur = rows[32];
        float s = midlo[c] + midhi[c];
        int bs = partial[cur] + boff[cur >> 8];
        int d = deg[cur];
        bool sh = bs >= p0, eh = bs + d <= p0 + 64;
        if (sh && eh)      aggb[(size_t)cur * 128 + c] = f2bf(s / (float)d);
        else if (sh)       pend[(size_t)blockIdx.x * 128 + c] = s;
        else if (eh)       pstart[(size_t)blockIdx.x * 128 + c] = s;
    }
}

// ---------------------------------------------------------------------------
// Node MFMA v5: same as R16/R17 plus nontemporal out stores (write-once
// 205MB stream should not displace L2 lines).
// ---------------------------------------------------------------------------
__global__ __launch_bounds__(512, 4) void node_mfma_kernel(
    const float* __restrict__ x, const float* __restrict__ u,
    const int* __restrict__ batch,
    const short* __restrict__ aggb,
    const int* __restrict__ deg, const int* __restrict__ partial,
    const int* __restrict__ boff,
    const float* __restrict__ pstart, const float* __restrict__ pend,
    const short* __restrict__ W2aF, const short* __restrict__ W2bF,
    const float* __restrict__ b2a, const float* __restrict__ b2b,
    float* __restrict__ out)
{
    __shared__ short lds[64 * 256];   // union: zb[64][192] then tb[64][256]
    __shared__ int   rmode[64];
    __shared__ float rinv[64];
    __shared__ int   rk[64];
    const int tid = threadIdx.x;
    const int node0 = blockIdx.x * 64;

    if (tid < 64) {
        int node = node0 + tid;
        int mode = 0, k = 0;
        float inv = 0.f;
        if (node < NN) {
            int d = deg[node];
            if (d > 0) {
                int bs = partial[node] + boff[node >> 8];
                k = bs >> 6;
                mode = ((bs & 63) + d > 64) ? 2 : 1;
                inv = 1.0f / (float)d;
            }
        }
        rmode[tid] = mode; rinv[tid] = inv; rk[tid] = k;
    }
    __syncthreads();

#pragma unroll
    for (int it = 0; it < 2; ++it) {
        int idx = it * 512 + tid;         // 1024 = 64 rows * 16 chunks
        int r = idx >> 4, ch = idx & 15;
        int node = node0 + r;
        int mode = rmode[r];
        s16x8 v = {0, 0, 0, 0, 0, 0, 0, 0};
        if (mode == 1) {
            v = *(const s16x8*)&aggb[(size_t)node * 128 + ch * 8];
        } else if (mode == 2) {
            float inv = rinv[r];
            int k = rk[r];
            const float* pe = &pend[(size_t)k * 128 + ch * 8];
            const float* ps = &pstart[(size_t)(k + 1) * 128 + ch * 8];
#pragma unroll
            for (int j = 0; j < 8; ++j)
                v[j] = f2bf((pe[j] + ps[j]) * inv);
        }
        int sw = (ch & ~7) | ((ch ^ r) & 7);
        *(s16x8*)&lds[r * 192 + sw * 8] = v;
    }
    if (tid < 64) {
        int r = tid, node = node0 + r;
        s16x8 p = {0, 0, 0, 0, 0, 0, 0, 0};
        if (node < NN) {
            p[0] = f2bf(x[node * 2]); p[1] = f2bf(x[node * 2 + 1]);
            int b = batch[node];
            p[2] = f2bf(u[b * 2]); p[3] = f2bf(u[b * 2 + 1]);
        }
        int sw = 16 | (r & 7);
        *(s16x8*)&lds[r * 192 + sw * 8] = p;
    } else if (tid < 256) {
        int t2 = tid - 64;
        int r = t2 & 63;
        int ch = 17 + (t2 >> 6);
        int sw = (ch & ~7) | ((ch ^ r) & 7);
        s16x8 zz = {0, 0, 0, 0, 0, 0, 0, 0};
        *(s16x8*)&lds[r * 192 + sw * 8] = zz;
    }
    __syncthreads();

    const int lane = tid & 63, nw = tid >> 6;
    const int l15 = lane & 15, lk = lane >> 4;

    f32x4 acc1[4][2];
#pragma unroll
    for (int mf = 0; mf < 4; ++mf)
#pragma unroll
        for (int nf = 0; nf < 2; ++nf)
            acc1[mf][nf] = (f32x4){0.f, 0.f, 0.f, 0.f};

#pragma unroll
    for (int ks = 0; ks < 5; ++ks) {
        s16x8 a[4], w[2];
        int cb = ks * 4 + lk;
#pragma unroll
        for (int mf = 0; mf < 4; ++mf) {
            int r = mf * 16 + l15;
            int sw = (cb & ~7) | ((cb ^ r) & 7);
            a[mf] = *(const s16x8*)&lds[r * 192 + sw * 8];
        }
#pragma unroll
        for (int nf = 0; nf < 2; ++nf)
            w[nf] = *(const s16x8*)&W2aF[((((nw * 2 + nf) * 5) + ks) * 64 + lane) * 8];
#pragma unroll
        for (int mf = 0; mf < 4; ++mf)
#pragma unroll
            for (int nf = 0; nf < 2; ++nf)
                acc1[mf][nf] = __builtin_amdgcn_mfma_f32_16x16x32_bf16(
                    w[nf], a[mf], acc1[mf][nf], 0, 0, 0);
    }
    __syncthreads();

#pragma unroll
    for (int nf = 0; nf < 2; ++nf) {
        int n0 = nw * 32 + nf * 16 + lk * 4;
        f32x4 bias = *(const f32x4*)&b2a[n0];
        int ch = n0 >> 3, off = n0 & 7;
#pragma unroll
        for (int mf = 0; mf < 4; ++mf) {
            int m = mf * 16 + l15;
            s16x4 pk;
#pragma unroll
            for (int j = 0; j < 4; ++j)
                pk[j] = f2bf(fmaxf(acc1[mf][nf][j] + bias[j], 0.f));
            int sw = (ch & ~7) | ((ch ^ m) & 7);
            *(s16x4*)&lds[m * 256 + sw * 8 + off] = pk;
        }
    }
    __syncthreads();

    f32x4 acc2[4][4];
#pragma unroll
    for (int mf = 0; mf < 4; ++mf)
#pragma unroll
        for (int nf = 0; nf < 4; ++nf)
            acc2[mf][nf] = (f32x4){0.f, 0.f, 0.f, 0.f};

#pragma unroll
    for (int ks = 0; ks < 8; ++ks) {
        s16x8 b[4], w[4];
        int cb = ks * 4 + lk;
#pragma unroll
        for (int mf = 0; mf < 4; ++mf) {
            int r = mf * 16 + l15;
            int sw = (cb & ~7) | ((cb ^ r) & 7);
            b[mf] = *(const s16x8*)&lds[r * 256 + sw * 8];
        }
#pragma unroll
        for (int nf = 0; nf < 4; ++nf)
            w[nf] = *(const s16x8*)&W2bF[((((nw * 4 + nf) * 8) + ks) * 64 + lane) * 8];
#pragma unroll
        for (int mf = 0; mf < 4; ++mf)
#pragma unroll
            for (int nf = 0; nf < 4; ++nf)
                acc2[mf][nf] = __builtin_amdgcn_mfma_f32_16x16x32_bf16(
                    w[nf], b[mf], acc2[mf][nf], 0, 0, 0);
    }

#pragma unroll
    for (int nf = 0; nf < 4; ++nf) {
        int n0 = nw * 64 + nf * 16 + lk * 4;
        f32x4 bias = *(const f32x4*)&b2b[n0];
#pragma unroll
        for (int mf = 0; mf < 4; ++mf) {
            int node = node0 + mf * 16 + l15;
            if (node < NN) {
                f32x4 o = acc2[mf][nf] + bias;
                __builtin_nontemporal_store(o, (f32x4*)&out[(size_t)node * 512 + n0]);
            }
        }
    }
}

extern "C" void kernel_launch(void* const* d_in, const int* in_sizes, int n_in,
                              void* d_out, int out_size, void* d_ws, size_t ws_size,
                              hipStream_t stream) {
    const float* x          = (const float*)d_in[0];
    const int*   edge_index = (const int*)d_in[1];
    const float* edge_attr  = (const float*)d_in[2];
    const float* u          = (const float*)d_in[3];
    const int*   batch      = (const int*)d_in[4];
    const float* W1a        = (const float*)d_in[5];
    const float* b1a        = (const float*)d_in[6];
    const float* W1b        = (const float*)d_in[7];
    const float* b1b        = (const float*)d_in[8];
    const float* W2a        = (const float*)d_in[9];
    const float* b2a        = (const float*)d_in[10];
    const float* W2b        = (const float*)d_in[11];
    const float* b2b        = (const float*)d_in[12];
    float* out = (float*)d_out;

    // workspace layout
    short* aggb   = (short*)d_ws;                        // [NN,128] bf16
    short* W2aF   = aggb + (size_t)NN * 128;             // [16*5*512] bf16
    short* W2bF   = W2aF + 16 * 5 * 512;                 // [32*8*512] bf16
    short* W1aT   = W2bF + 32 * 8 * 512;                 // [64,32]   bf16
    short* W1bT   = W1aT + 64 * 32;                      // [128,64]  bf16
    int*   deg    = (int*)(W1bT + 128 * 64);             // [NP]
    int*   cnt2   = deg + NP;                            // [NP] (memset with deg)
    int*   partial= cnt2 + NP;                           // [NP]
    int*   bsum   = partial + NP;                        // [512]
    int*   boff   = bsum + 512;                          // [512]
    int*   rowp   = boff + 512;                          // [NE]
    float* pstart = (float*)(rowp + NE);                 // [NBE,128]
    float* pend   = pstart + (size_t)NBE * 128;          // [NBE,128]
    short* in_csr = (short*)(pend + (size_t)NBE * 128);  // [NE,8] bf16

    hipMemsetAsync(deg, 0, 2 * NP * sizeof(int), stream);

    hist_prep_kernel<<<(NE + 255) / 256, 256, 0, stream>>>(
        edge_index, deg, W2a, W2b, W1a, W1b, W2aF, W2bF, W1aT, W1bT);
    scan1_kernel<<<NB, 256, 0, stream>>>(deg, partial, bsum);
    scan2_kernel<<<1, 512, 0, stream>>>(bsum, boff);
    fill_kernel <<<(NE + 255) / 256, 256, 0, stream>>>(edge_index, x, edge_attr,
                                                       partial, boff, cnt2,
                                                       rowp, in_csr);

    edge_fused_kernel<<<NBE, 256, 0, stream>>>(
        in_csr, rowp, W1aT, W1bT, b1a, b1b,
        partial, boff, deg, aggb, pstart, pend);

    node_mfma_kernel<<<(NN + 63) / 64, 512, 0, stream>>>(
        x, u, batch, aggb, deg, partial, boff, pstart, pend,
        W2aF, W2bF, b2a, b2b, out);
}